// Round 14
// baseline (1299.078 us; speedup 1.0000x reference)
//
#include <hip/hip_runtime.h>
#include <cmath>
#include <cstddef>

#define NN 3000
#define MM 6000
#define FV 128
#define FE 64
#define H1 256
#define H2 128
#define NC 16
#define E2 12000

// pack-tile geometry: 128 cols x 32 k bf16 = 8192 B per tile
#define CT_E 47
#define KT_E 94
#define CT_M 24
#define KT_M 188
#define KT_A 188        // j-tiles (32-col) of A-pack
#define NPK_M 94        // j-tiles of mult1 pack
#define PKE_BYTES ((size_t)CT_E * KT_E * 8192)    // 36,192,256
#define PKM_BYTES ((size_t)CT_M * KT_M * 8192)    // 36,962,304
#define APK_BYTES ((size_t)CT_E * KT_A * 8192)    // 72,384,512

static inline int cdiv(int a, int b) { return (a + b - 1) / b; }

typedef __attribute__((ext_vector_type(8))) short short8;
typedef __attribute__((ext_vector_type(4))) float f32x4;

__device__ inline void atomicMaxFloat(float* addr, float v) {
  if (v >= 0.f) atomicMax((int*)addr, __float_as_int(v));
  else          atomicMin((unsigned int*)addr, __float_as_uint(v));
}

__device__ inline unsigned short b2h(float x) {   // RTN-even fp32->bf16
  unsigned int u = __float_as_uint(x);
  return (unsigned short)((u + 0x7FFFu + ((u >> 16) & 1u)) >> 16);
}

__device__ inline void bsplit(float x, unsigned short& h, unsigned short& l) {
  h = b2h(x);
  float hf = __uint_as_float(((unsigned int)h) << 16);
  l = b2h(x - hf);
}

__global__ void k_fill(float* p, float v, int n) {
  int i = blockIdx.x * blockDim.x + threadIdx.x;
  if (i < n) p[i] = v;
}

__global__ void k_fill_bias(float* p, const float* __restrict__ bias, int nmask, int total) {
  int i = blockIdx.x * blockDim.x + threadIdx.x;
  if (i < total) p[i] = bias[i & nmask];
}

__global__ void k_relu_copy(const float* __restrict__ in, float* __restrict__ out, int n) {
  int i = blockIdx.x * blockDim.x + threadIdx.x;
  if (i < n) out[i] = fmaxf(in[i], 0.f);
}

__global__ void k_relu(float* p, int n) {
  int i = blockIdx.x * blockDim.x + threadIdx.x;
  if (i < n) p[i] = fmaxf(p[i], 0.f);
}

__global__ void k_deg_count(const int* __restrict__ dst, float* deg, int ne) {
  int e = blockIdx.x * blockDim.x + threadIdx.x;
  if (e < ne) atomicAdd(&deg[dst[e]], 1.f);
}

__global__ void k_dinv(float* deg, int n) {
  int i = blockIdx.x * blockDim.x + threadIdx.x;
  if (i < n) deg[i] = rsqrtf(deg[i] + 1.0f);
}

__global__ void k_gcn_init(const float* __restrict__ xw, const float* __restrict__ dinv,
                           const float* __restrict__ bias, float* __restrict__ out,
                           int n, int flog2) {
  int idx = blockIdx.x * blockDim.x + threadIdx.x;
  int F = 1 << flog2;
  if (idx < n * F) {
    int i = idx >> flog2;
    int f = idx & (F - 1);
    float di = dinv[i];
    out[idx] = xw[idx] * di * di + bias[f];
  }
}

__global__ void k_gcn_scatter(const float* __restrict__ xw, const int* __restrict__ src,
                              const int* __restrict__ dst, const float* __restrict__ dinv,
                              float* __restrict__ out, int ne, int flog2) {
  int idx = blockIdx.x * blockDim.x + threadIdx.x;
  int F = 1 << flog2;
  if (idx < ne * F) {
    int e = idx >> flog2;
    int f = idx & (F - 1);
    int s = src[e], d = dst[e];
    atomicAdd(&out[d * F + f], xw[s * F + f] * dinv[s] * dinv[d]);
  }
}

__global__ void k_rowdot(const float* __restrict__ Xv, const float* __restrict__ p,
                         float* __restrict__ out, int rows, int K) {
  int row = blockIdx.x * 4 + (threadIdx.x >> 6);
  int lane = threadIdx.x & 63;
  if (row >= rows) return;
  float acc = 0.f;
  for (int k = lane; k < K; k += 64) acc += Xv[(size_t)row * K + k] * p[k];
  for (int off = 32; off > 0; off >>= 1) acc += __shfl_xor(acc, off);
  if (lane == 0) out[row] = acc;
}

// fallback-path: Bc = HeW/cmax ; Zh prefilled with bias (FE = 64)
__global__ void k_prep(const float* __restrict__ HeW, const float* __restrict__ cmax,
                       const float* __restrict__ bias,
                       float* __restrict__ Bc, float* __restrict__ Zh, int total) {
  int idx = blockIdx.x * blockDim.x + threadIdx.x;
  if (idx < total) {
    Bc[idx] = HeW[idx] / cmax[idx >> 6];
    Zh[idx] = bias[idx & 63];
  }
}

// big-path: Bpk tile = bf16(HeW/cmax) packed; Zh prefilled with bias. One block per kt.
__global__ void k_prep_pack(const float* __restrict__ HeW, const float* __restrict__ cmax,
                            const float* __restrict__ bias,
                            float* __restrict__ Zh, char* __restrict__ Bpk, int Kd) {
  int kt = blockIdx.x;
  int t = threadIdx.x;
  int f = t >> 2, g = t & 3;
  float bf = bias[f];
  unsigned short hv[8];
#pragma unroll
  for (int e = 0; e < 8; ++e) {
    int k = kt * 32 + g * 8 + e;
    float v = 0.f;
    if (k < Kd) {
      v = HeW[(size_t)k * 64 + f] / cmax[k];
      Zh[(size_t)k * 64 + f] = bf;
    }
    hv[e] = b2h(v);
  }
  uint4 H;
  H.x = (unsigned)hv[0] | ((unsigned)hv[1] << 16);
  H.y = (unsigned)hv[2] | ((unsigned)hv[3] << 16);
  H.z = (unsigned)hv[4] | ((unsigned)hv[5] << 16);
  H.w = (unsigned)hv[6] | ((unsigned)hv[7] << 16);
  *(uint4*)(Bpk + (size_t)kt * 4096 + f * 64 + ((g ^ ((f >> 1) & 3)) * 16)) = H;
}

// pack g [Kd][128] fp32 -> 128-col B tiles (8192 B per kt)
__global__ void k_pack_g(const float* __restrict__ g, char* __restrict__ gpk, int Kd) {
  int kt = blockIdx.x;
  int t = threadIdx.x;
#pragma unroll
  for (int it = 0; it < 2; ++it) {
    int idx = it * 256 + t;
    int f = idx >> 2, gsw = idx & 3;
    int gq = gsw ^ ((f >> 1) & 3);
    unsigned short hv[8];
#pragma unroll
    for (int e = 0; e < 8; ++e) {
      int k = kt * 32 + gq * 8 + e;
      float v = (k < Kd) ? g[(size_t)k * 128 + f] : 0.f;
      hv[e] = b2h(v);
    }
    uint4 H;
    H.x = (unsigned)hv[0] | ((unsigned)hv[1] << 16);
    H.y = (unsigned)hv[2] | ((unsigned)hv[3] << 16);
    H.z = (unsigned)hv[4] | ((unsigned)hv[5] << 16);
    H.w = (unsigned)hv[6] | ((unsigned)hv[7] << 16);
    *(uint4*)(gpk + (size_t)kt * 8192 + idx * 16) = H;
  }
}

// ===== pack kernels: bf16 tiles in the exact (swizzled) LDS image =====
// image: element (c,k) at byte  c*64 + ((k>>3) ^ ((c>>1)&3))*16 + (k&7)*2
__global__ void k_pack_edge(const float* __restrict__ T, const float* __restrict__ svp,
                            char* __restrict__ ph, char* __restrict__ pl,
                            float* __restrict__ cmax,
                            int scaled, int Md, int Kd, int nkt) {
  int ct = blockIdx.x, kt = blockIdx.y;
  size_t base = ((size_t)ct * nkt + kt) * 8192;
  int t = threadIdx.x;
  if (scaled && kt == 0 && t < 128) {
    int cc = ct * 128 + t;
    if (cc < Md) cmax[cc] = -INFINITY;
  }
#pragma unroll
  for (int it = 0; it < 2; ++it) {
    int tau = it * 256 + t;
    int c = tau & 127;
    int g = tau >> 7;
    int gc = ct * 128 + c;
    int off = c * 64 + ((g ^ ((c >> 1) & 3)) * 16);
    unsigned short hv[8], lv[8];
#pragma unroll
    for (int e = 0; e < 8; ++e) {
      int k = kt * 32 + g * 8 + e;
      float v = 0.f;
      if (k < Kd && gc < Md) {
        v = T[(size_t)k * Md + gc];
        if (scaled) v *= svp[k];
      }
      bsplit(v, hv[e], lv[e]);
    }
    uint4 H, L;
    H.x = (unsigned)hv[0] | ((unsigned)hv[1] << 16);
    H.y = (unsigned)hv[2] | ((unsigned)hv[3] << 16);
    H.z = (unsigned)hv[4] | ((unsigned)hv[5] << 16);
    H.w = (unsigned)hv[6] | ((unsigned)hv[7] << 16);
    *(uint4*)(ph + base + off) = H;
    if (pl) {
      L.x = (unsigned)lv[0] | ((unsigned)lv[1] << 16);
      L.y = (unsigned)lv[2] | ((unsigned)lv[3] << 16);
      L.z = (unsigned)lv[4] | ((unsigned)lv[5] << 16);
      L.w = (unsigned)lv[6] | ((unsigned)lv[7] << 16);
      *(uint4*)(pl + base + off) = L;
    }
  }
}

// transposed variant for mult1: value = T[node][edge], c over nodes, k over edges
__global__ void k_pack_tt(const float* __restrict__ T, const float* __restrict__ sep,
                          char* __restrict__ ph, char* __restrict__ pl,
                          int scaled, int Mt, int Kt, int nkt) {
  int ct = blockIdx.x, kt = blockIdx.y;
  size_t base = ((size_t)ct * nkt + kt) * 8192;
  int t = threadIdx.x;
#pragma unroll
  for (int it = 0; it < 2; ++it) {
    int tau = it * 256 + t;
    int c = tau >> 2;
    int g = tau & 3;
    int node = ct * 128 + c;
    int off = c * 64 + ((g ^ ((c >> 1) & 3)) * 16);
    unsigned short hv[8], lv[8];
#pragma unroll
    for (int e = 0; e < 8; ++e) {
      int k = kt * 32 + g * 8 + e;
      float v = 0.f;
      if (node < Mt && k < Kt) {
        v = T[(size_t)node * Kt + k];
        if (scaled) v *= sep[k];
      }
      bsplit(v, hv[e], lv[e]);
    }
    uint4 H, L;
    H.x = (unsigned)hv[0] | ((unsigned)hv[1] << 16);
    H.y = (unsigned)hv[2] | ((unsigned)hv[3] << 16);
    H.z = (unsigned)hv[4] | ((unsigned)hv[5] << 16);
    H.w = (unsigned)hv[6] | ((unsigned)hv[7] << 16);
    *(uint4*)(ph + base + off) = H;
    if (pl) {
      L.x = (unsigned)lv[0] | ((unsigned)lv[1] << 16);
      L.y = (unsigned)lv[2] | ((unsigned)lv[3] << 16);
      L.z = (unsigned)lv[4] | ((unsigned)lv[5] << 16);
      L.w = (unsigned)lv[6] | ((unsigned)lv[7] << 16);
      *(uint4*)(pl + base + off) = L;
    }
  }
}

// ===== SYRK MFMA kernel: Out_L = T^T diag(sv_L) T — upper-tri tiles, multi-layer grid ====
// ONE unscaled pack for both operands; B-frag scaled by sv[k] in registers.
// SVB = bytes of sv LDS region. EPI=1: adj/colmax/pack epilogue; EPI=0: pack only.
template <int EPI, int SVB>
__global__ __launch_bounds__(256) void k_tsvt_sym(const char* __restrict__ pA,
                                                  const float* __restrict__ svg,
                                                  int svn, int svStride,
                                                  const float* __restrict__ adj,
                                                  char* __restrict__ OpkBase,
                                                  float* __restrict__ cmaxBase,
                                                  int Md, int nkt, int nbt, int npk,
                                                  int ntri, size_t opkStride,
                                                  int cmaxStride) {
  __shared__ __align__(16) char smem[32768 + SVB];
  constexpr int SVN = SVB / 4;
  const int tid = threadIdx.x;
  const int lane = tid & 63;
  const int w = tid >> 6;
  const int wr = w >> 1;
  const int wc = w & 1;
  const int r16 = lane & 15;
  const int kb = lane >> 4;

  // bijective XCD remap over full grid, then layer + triangle decode
  int nwg = gridDim.x;
  int orig = blockIdx.x;
  int q = nwg >> 3, r = nwg & 7;
  int xcd = orig & 7, pos = orig >> 3;
  int wgid = (xcd < r ? xcd * (q + 1) : r * (q + 1) + (xcd - r) * q) + pos;
  int layer = wgid / ntri;
  int tri = wgid - layer * ntri;
  int bi = 0, rem = tri;
  while (rem >= nbt - bi) { rem -= nbt - bi; ++bi; }
  int bj = bi + rem;

  const int i0 = bi * 128, j0 = bj * 128;
  const float* sv = svg + (size_t)layer * svStride;
  char* Opk = OpkBase + (size_t)layer * opkStride;
  float* cmax = cmaxBase ? (cmaxBase + (size_t)layer * cmaxStride) : nullptr;

  const char* srcA = pA + (size_t)bi * nkt * 8192;
  const char* srcB = pA + (size_t)bj * nkt * 8192;
  const int c4 = w * 4;
  float* svl = (float*)(smem + 32768);

  auto stage = [&](int kt, int buf) {
#pragma unroll
    for (int o = 0; o < 4; ++o) {
      int c = c4 + o;
      int sel = c >> 3, sub = c & 7;
      const char* s = (sel ? srcB : srcA) + (size_t)kt * 8192 + sub * 1024 + lane * 16;
      __builtin_amdgcn_global_load_lds(
          (const __attribute__((address_space(1))) void*)s,
          (__attribute__((address_space(3))) void*)(smem + buf * 16384 + c * 1024 + lane * 16),
          16, 0, 0);
    }
  };

  f32x4 acc[4][4];
#pragma unroll
  for (int a = 0; a < 4; ++a)
#pragma unroll
    for (int b = 0; b < 4; ++b) acc[a][b] = 0.f;

  stage(0, 0);
  for (int k = tid; k < SVN; k += 256) svl[k] = (k < svn) ? sv[k] : 0.f;
  __syncthreads();
  int cur = 0;
  for (int kt = 0; kt < nkt; ++kt) {
    if (kt + 1 < nkt) stage(kt + 1, cur ^ 1);
    const char* sA = smem + cur * 16384;
    const char* sB = sA + 8192;

    // per-step sv chunk (broadcast within 16-lane groups)
    const float* svp8 = (const float*)((const char*)svl + kt * 128 + kb * 32);
    float4 sva = *(const float4*)svp8;
    float4 svb = *(const float4*)(svp8 + 4);
    float svv[8] = {sva.x, sva.y, sva.z, sva.w, svb.x, svb.y, svb.z, svb.w};

    short8 bh[4];
#pragma unroll
    for (int nj = 0; nj < 4; ++nj) {
      int col = wc * 64 + nj * 16 + r16;
      uint4 wv = *(const uint4*)(sB + col * 64 + ((kb ^ ((col >> 1) & 3)) * 16));
      unsigned int ws[4] = {wv.x, wv.y, wv.z, wv.w};
      unsigned int rw[4];
#pragma unroll
      for (int p = 0; p < 4; ++p) {
        float lo = __uint_as_float(ws[p] << 16) * svv[2 * p];
        float hi = __uint_as_float(ws[p] & 0xFFFF0000u) * svv[2 * p + 1];
        asm("v_cvt_pk_bf16_f32 %0, %1, %2" : "=v"(rw[p]) : "v"(lo), "v"(hi));
      }
      uint4 rv;
      rv.x = rw[0]; rv.y = rw[1]; rv.z = rw[2]; rv.w = rw[3];
      bh[nj] = *(short8*)&rv;
    }
#pragma unroll
    for (int mi = 0; mi < 4; ++mi) {
      int row = wr * 64 + mi * 16 + r16;
      short8 ah = *(const short8*)(sA + row * 64 + ((kb ^ ((row >> 1) & 3)) * 16));
#pragma unroll
      for (int nj = 0; nj < 4; ++nj)
        acc[mi][nj] = __builtin_amdgcn_mfma_f32_16x16x32_bf16(ah, bh[nj], acc[mi][nj], 0, 0, 0);
    }
    __syncthreads();
    cur ^= 1;
  }

  // ---- epilogue ----
  // Phase 0: raw m2 bf16 into LDS at (jl, il): byte jl*256 + ((il*2) ^ ((jl&7)<<4))
#pragma unroll
  for (int nj = 0; nj < 4; ++nj) {
    int jl = wc * 64 + nj * 16 + r16;
#pragma unroll
    for (int mi = 0; mi < 4; ++mi) {
      int ilb = wr * 64 + mi * 16 + kb * 4;
      f32x4 a = acc[mi][nj];
#pragma unroll
      for (int rr = 0; rr < 4; ++rr) {
        int il = ilb + rr;
        *(unsigned short*)(smem + jl * 256 + ((il * 2) ^ ((jl & 7) << 4))) = b2h(a[rr]);
      }
    }
  }

  // Phase 1: direct writes (i <= j)  [C/D layout per m89]
#pragma unroll
  for (int nj = 0; nj < 4; ++nj) {
    int j = j0 + wc * 64 + nj * 16 + r16;
    float cm = -INFINITY;
    bool jok = (j < Md);
#pragma unroll
    for (int mi = 0; mi < 4; ++mi) {
      int ib = i0 + wr * 64 + mi * 16 + kb * 4;
      f32x4 a = acc[mi][nj];
#pragma unroll
      for (int rr = 0; rr < 4; ++rr) {
        int i = ib + rr;
        if (i < Md && jok && i <= j) {
          float v = a[rr];
          if (EPI == 1) {
            if (i == j) v = 1.0f;
            v *= adj[(size_t)i * Md + j];
            cm = fmaxf(cm, v);
          }
          *(unsigned short*)(Opk + ((size_t)(i >> 7) * npk + (j >> 5)) * 8192
              + (i & 127) * 64 + ((((j >> 3) & 3) ^ ((i >> 1) & 3)) * 16) + (j & 7) * 2)
              = b2h(v);
        }
      }
    }
    if (EPI == 1) {
      cm = fmaxf(cm, __shfl_xor(cm, 16));
      cm = fmaxf(cm, __shfl_xor(cm, 32));
      if (kb == 0 && jok) atomicMaxFloat(&cmax[j], cm);
    }
  }

  // Phase 2: mirror writes (j, i), i < j — coalesced via the LDS transpose
  __syncthreads();
  {
    int ic = tid & 127;
    int i = i0 + ic;
    int rowpar = tid >> 7;
    bool iok = (i < Md);
    float lm = -INFINITY;
#pragma unroll 8
    for (int m = 0; m < 64; ++m) {
      int jr = m * 2 + rowpar;
      int j = j0 + jr;
      if (iok && j < Md && i < j) {
        unsigned short hv =
            *(unsigned short*)(smem + jr * 256 + ((ic * 2) ^ ((jr & 7) << 4)));
        float vm = __uint_as_float(((unsigned int)hv) << 16);
        if (EPI == 1) {
          float a2 = vm * adj[(size_t)j * Md + i];
          *(unsigned short*)(Opk + ((size_t)(j >> 7) * npk + (i >> 5)) * 8192
              + (j & 127) * 64 + ((((i >> 3) & 3) ^ ((j >> 1) & 3)) * 16) + (i & 7) * 2)
              = b2h(a2);
          lm = fmaxf(lm, a2);
        } else {
          *(unsigned short*)(Opk + ((size_t)(j >> 7) * npk + (i >> 5)) * 8192
              + (j & 127) * 64 + ((((i >> 3) & 3) ^ ((j >> 1) & 3)) * 16) + (i & 7) * 2)
              = b2h(vm);
        }
      }
    }
    if (EPI == 1 && iok && lm > -INFINITY) atomicMaxFloat(&cmax[i], lm);
  }
}

// ===== MFMA kernel: Zh += Apack @ Bcpack (M x 64), split-K atomics =====
__global__ __launch_bounds__(256) void k_zh(const char* __restrict__ Apk,
                                            const char* __restrict__ Bpk,
                                            float* __restrict__ Zh,
                                            int Mn, int nktA, int zchunk) {
  __shared__ __align__(16) char smem[12288];      // A 8KB + B 4KB
  const int tid = threadIdx.x;
  const int lane = tid & 63;
  const int w = tid >> 6;
  const int r16 = lane & 15;
  const int kb = lane >> 4;
  const int bi = blockIdx.x;
  const int kt0 = blockIdx.y * zchunk;
  const int kt1 = min(nktA, kt0 + zchunk);
  const int i0 = bi * 128;

  f32x4 acc[2][4];
#pragma unroll
  for (int a = 0; a < 2; ++a)
#pragma unroll
    for (int b = 0; b < 4; ++b) acc[a][b] = 0.f;

  for (int kt = kt0; kt < kt1; ++kt) {
    const char* As = Apk + ((size_t)bi * nktA + kt) * 8192;
    const char* Bs = Bpk + (size_t)kt * 4096;
    __builtin_amdgcn_global_load_lds(
        (const __attribute__((address_space(1))) void*)(As + tid * 16),
        (__attribute__((address_space(3))) void*)(smem + tid * 16), 16, 0, 0);
    __builtin_amdgcn_global_load_lds(
        (const __attribute__((address_space(1))) void*)(As + 4096 + tid * 16),
        (__attribute__((address_space(3))) void*)(smem + 4096 + tid * 16), 16, 0, 0);
    __builtin_amdgcn_global_load_lds(
        (const __attribute__((address_space(1))) void*)(Bs + tid * 16),
        (__attribute__((address_space(3))) void*)(smem + 8192 + tid * 16), 16, 0, 0);
    __syncthreads();
    short8 bh[4];
#pragma unroll
    for (int nj = 0; nj < 4; ++nj) {
      int f = nj * 16 + r16;
      bh[nj] = *(const short8*)(smem + 8192 + f * 64 + ((kb ^ ((f >> 1) & 3)) * 16));
    }
#pragma unroll
    for (int mi = 0; mi < 2; ++mi) {
      int c = w * 32 + mi * 16 + r16;
      short8 ah = *(const short8*)(smem + c * 64 + ((kb ^ ((c >> 1) & 3)) * 16));
#pragma unroll
      for (int nj = 0; nj < 4; ++nj)
        acc[mi][nj] = __builtin_amdgcn_mfma_f32_16x16x32_bf16(ah, bh[nj], acc[mi][nj], 0, 0, 0);
    }
    __syncthreads();
  }
#pragma unroll
  for (int mi = 0; mi < 2; ++mi) {
    int ib = i0 + w * 32 + mi * 16 + kb * 4;
#pragma unroll
    for (int nj = 0; nj < 4; ++nj) {
      int f = nj * 16 + r16;
      f32x4 a = acc[mi][nj];
#pragma unroll
      for (int r = 0; r < 4; ++r) {
        int i = ib + r;
        if (i < Mn) atomicAdd(&Zh[(size_t)i * 64 + f], a[r]);
      }
    }
  }
}

// ===== MFMA kernel: C(+bias prefilled) += Apack @ Bpack128 (M x 128), split-K atomics =====
__global__ __launch_bounds__(256) void k_zh128(const char* __restrict__ Apk,
                                               const char* __restrict__ Bpk,
                                               float* __restrict__ C,
                                               int Mn, int nktA, int zchunk) {
  __shared__ __align__(16) char smem[16384];      // A 8KB + B 8KB
  const int tid = threadIdx.x;
  const int lane = tid & 63;
  const int w = tid >> 6;
  const int r16 = lane & 15;
  const int kb = lane >> 4;
  const int bi = blockIdx.x;
  const int kt0 = blockIdx.y * zchunk;
  const int kt1 = min(nktA, kt0 + zchunk);
  const int i0 = bi * 128;

  f32x4 acc[2][8];
#pragma unroll
  for (int a = 0; a < 2; ++a)
#pragma unroll
    for (int b = 0; b < 8; ++b) acc[a][b] = 0.f;

  for (int kt = kt0; kt < kt1; ++kt) {
    const char* As = Apk + ((size_t)bi * nktA + kt) * 8192;
    const char* Bs = Bpk + (size_t)kt * 8192;
#pragma unroll
    for (int o = 0; o < 4; ++o) {
      int idx = o * 256 + tid;
      const char* s = (idx < 512) ? (As + idx * 16) : (Bs + (idx - 512) * 16);
      __builtin_amdgcn_global_load_lds(
          (const __attribute__((address_space(1))) void*)s,
          (__attribute__((address_space(3))) void*)(smem + idx * 16), 16, 0, 0);
    }
    __syncthreads();
    short8 bh[8];
#pragma unroll
    for (int nj = 0; nj < 8; ++nj) {
      int f = nj * 16 + r16;
      bh[nj] = *(const short8*)(smem + 8192 + f * 64 + ((kb ^ ((f >> 1) & 3)) * 16));
    }
#pragma unroll
    for (int mi = 0; mi < 2; ++mi) {
      int c = w * 32 + mi * 16 + r16;
      short8 ah = *(const short8*)(smem + c * 64 + ((kb ^ ((c >> 1) & 3)) * 16));
#pragma unroll
      for (int nj = 0; nj < 8; ++nj)
        acc[mi][nj] = __builtin_amdgcn_mfma_f32_16x16x32_bf16(ah, bh[nj], acc[mi][nj], 0, 0, 0);
    }
    __syncthreads();
  }
#pragma unroll
  for (int mi = 0; mi < 2; ++mi) {
    int ib = i0 + w * 32 + mi * 16 + kb * 4;
#pragma unroll
    for (int nj = 0; nj < 8; ++nj) {
      int f = nj * 16 + r16;
      f32x4 a = acc[mi][nj];
#pragma unroll
      for (int r = 0; r < 4; ++r) {
        int i = ib + r;
        if (i < Mn) atomicAdd(&C[(size_t)i * 128 + f], a[r]);
      }
    }
  }
}

// ===== fallback MFMA kernel with in-kernel conversion (3-term) =====
template <int EPI>
__global__ __launch_bounds__(256) void k_tsvt_cvt(const float* __restrict__ Tmat,
                                                  const float* __restrict__ svp,
                                                  const float* __restrict__ adj,
                                                  float* __restrict__ Out,
                                                  float* __restrict__ cmax,
                                                  int Md, int Kd) {
  __shared__ __align__(16) unsigned short sAh[128 * 32];
  __shared__ __align__(16) unsigned short sAl[128 * 32];
  __shared__ __align__(16) unsigned short sBh[128 * 32];
  __shared__ __align__(16) unsigned short sBl[128 * 32];
  const int tid = threadIdx.x;
  const int lane = tid & 63;
  const int w = tid >> 6;
  const int wr = w >> 1, wc = w & 1;
  const int r16 = lane & 15;
  const int kb = lane >> 4;
  const int i0 = blockIdx.y * 128;
  const int j0 = blockIdx.x * 128;
  f32x4 acc[4][4];
#pragma unroll
  for (int a = 0; a < 4; ++a)
#pragma unroll
    for (int b = 0; b < 4; ++b) acc[a][b] = 0.f;
  for (int k0 = 0; k0 < Kd; k0 += 32) {
#pragma unroll
    for (int it = 0; it < 4; ++it) {
      int s = tid + it * 256;
      int ci = s & 127;
      int kq = s >> 7;
      int kk = kq * 4;
      int kbq = kq >> 1, half = kq & 1;
      int off = ci * 64 + (kbq ^ ((ci >> 1) & 3)) * 16 + half * 8;
      float va[4];
#pragma unroll
      for (int e = 0; e < 4; ++e) {
        int k = k0 + kk + e;
        int c = i0 + ci;
        va[e] = (k < Kd && c < Md) ? Tmat[(size_t)k * Md + c] : 0.f;
      }
      unsigned short h0, h1, h2, h3, l0, l1, l2, l3;
      bsplit(va[0], h0, l0); bsplit(va[1], h1, l1);
      bsplit(va[2], h2, l2); bsplit(va[3], h3, l3);
      uint2 hp, lp;
      hp.x = (unsigned)h0 | ((unsigned)h1 << 16); hp.y = (unsigned)h2 | ((unsigned)h3 << 16);
      lp.x = (unsigned)l0 | ((unsigned)l1 << 16); lp.y = (unsigned)l2 | ((unsigned)l3 << 16);
      *(uint2*)((char*)sAh + off) = hp;
      *(uint2*)((char*)sAl + off) = lp;
      float vb[4];
#pragma unroll
      for (int e = 0; e < 4; ++e) {
        int k = k0 + kk + e;
        int c = j0 + ci;
        float svv = (k < Kd) ? svp[k] : 0.f;
        vb[e] = (k < Kd && c < Md) ? Tmat[(size_t)k * Md + c] * svv : 0.f;
      }
      bsplit(vb[0], h0, l0); bsplit(vb[1], h1, l1);
      bsplit(vb[2], h2, l2); bsplit(vb[3], h3, l3);
      hp.x = (unsigned)h0 | ((unsigned)h1 << 16); hp.y = (unsigned)h2 | ((unsigned)h3 << 16);
      lp.x = (unsigned)l0 | ((unsigned)l1 << 16); lp.y = (unsigned)l2 | ((unsigned)l3 << 16);
      *(uint2*)((char*)sBh + off) = hp;
      *(uint2*)((char*)sBl + off) = lp;
    }
    __syncthreads();
    short8 bh[4], bl[4];
#pragma unroll
    for (int nj = 0; nj < 4; ++nj) {
      int col = wc * 64 + nj * 16 + r16;
      int off = col * 64 + ((kb ^ ((col >> 1) & 3)) * 16);
      bh[nj] = *(const short8*)((const char*)sBh + off);
      bl[nj] = *(const short8*)((const char*)sBl + off);
    }
#pragma unroll
    for (int mi = 0; mi < 4; ++mi) {
      int row = wr * 64 + mi * 16 + r16;
      int off = row * 64 + ((kb ^ ((row >> 1) & 3)) * 16);
      short8 ah = *(const short8*)((const char*)sAh + off);
      short8 al = *(const short8*)((const char*)sAl + off);
#pragma unroll
      for (int nj = 0; nj < 4; ++nj) {
        acc[mi][nj] = __builtin_amdgcn_mfma_f32_16x16x32_bf16(ah, bh[nj], acc[mi][nj], 0, 0, 0);
        acc[mi][nj] = __builtin_amdgcn_mfma_f32_16x16x32_bf16(ah, bl[nj], acc[mi][nj], 0, 0, 0);
        acc[mi][nj] = __builtin_amdgcn_mfma_f32_16x16x32_bf16(al, bh[nj], acc[mi][nj], 0, 0, 0);
      }
    }
    __syncthreads();
  }
#pragma unroll
  for (int nj = 0; nj < 4; ++nj) {
    int j = j0 + wc * 64 + nj * 16 + r16;
    float cm = -INFINITY;
#pragma unroll
    for (int mi = 0; mi < 4; ++mi) {
      int ib = i0 + wr * 64 + mi * 16 + kb * 4;
      f32x4 a = acc[mi][nj];
#pragma unroll
      for (int r = 0; r < 4; ++r) {
        int i = ib + r;
        if (i < Md && j < Md) {
          float v = a[r];
          if (EPI == 1) {
            if (i == j) v = 1.0f;
            v *= adj[(size_t)i * Md + j];
            Out[(size_t)i * Md + j] = v;
            cm = fmaxf(cm, v);
          } else {
            Out[(size_t)i * Md + j] = v;
          }
        }
      }
    }
    if (EPI == 1) {
      cm = fmaxf(cm, __shfl_xor(cm, 16));
      cm = fmaxf(cm, __shfl_xor(cm, 32));
      if (kb == 0 && j < Md) atomicMaxFloat(&cmax[j], cm);
    }
  }
}

// -------- generic 64x64 tiled fp32 GEMM ----
template <int SPLITK, int NT>
__global__ __launch_bounds__(256) void k_gemm64(const float* __restrict__ Am,
                                                const float* __restrict__ Bm,
                                                const float* __restrict__ bias,
                                                const float* __restrict__ kscale,
                                                float* __restrict__ C,
                                                int Mn, int Nn, int Kn, int relu) {
  __shared__ float As[16][68];
  __shared__ float Bs[16][68];
  int i0 = blockIdx.y * 64, j0 = blockIdx.x * 64;
  int kchunk = (Kn + SPLITK - 1) / SPLITK;
  int ks = blockIdx.z * kchunk;
  int ke = min(Kn, ks + kchunk);
  int tid = threadIdx.x;
  int tx = tid & 15, ty = tid >> 4;
  float acc[4][4] = {};
  for (int k0 = ks; k0 < ke; k0 += 16) {
#pragma unroll
    for (int l0 = 0; l0 < 1024; l0 += 256) {
      int l = l0 + tid;
      int i = l >> 4, k = l & 15;
      float v = 0.f;
      if (i0 + i < Mn && k0 + k < ke) {
        v = NT ? __builtin_nontemporal_load(&Am[(size_t)(i0 + i) * Kn + (k0 + k)])
               : Am[(size_t)(i0 + i) * Kn + (k0 + k)];
        if (kscale) v *= kscale[k0 + k];
      }
      As[k][i] = v;
    }
#pragma unroll
    for (int l0 = 0; l0 < 1024; l0 += 256) {
      int l = l0 + tid;
      int k = l >> 6, j = l & 63;
      float v = 0.f;
      if (k0 + k < ke && j0 + j < Nn) v = Bm[(size_t)(k0 + k) * Nn + (j0 + j)];
      Bs[k][j] = v;
    }
    __syncthreads();
#pragma unroll
    for (int k = 0; k < 16; ++k) {
      const float4 av = *(const float4*)&As[k][ty * 4];
      const float4 bv = *(const float4*)&Bs[k][tx * 4];
      float a_[4] = {av.x, av.y, av.z, av.w};
      float b_[4] = {bv.x, bv.y, bv.z, bv.w};
#pragma unroll
      for (int ri = 0; ri < 4; ++ri)
#pragma unroll
        for (int rj = 0; rj < 4; ++rj)
          acc[ri][rj] = fmaf(a_[ri], b_[rj], acc[ri][rj]);
    }
    __syncthreads();
  }
#pragma unroll
  for (int ri = 0; ri < 4; ++ri) {
    int i = i0 + ty * 4 + ri;
    if (i >= Mn) continue;
#pragma unroll
    for (int rj = 0; rj < 4; ++rj) {
      int j = j0 + tx * 4 + rj;
      if (j >= Nn) continue;
      float v = acc[ri][rj];
      if (SPLITK > 1) {
        atomicAdd(&C[(size_t)i * Nn + j], v);
      } else {
        if (bias) v += bias[j];
        if (relu) v = fmaxf(v, 0.f);
        C[(size_t)i * Nn + j] = v;
      }
    }
  }
}

__global__ void k_transpose(const float* __restrict__ in, float* __restrict__ out,
                            int rows, int cols) {
  __shared__ float tile[32][33];
  int c0 = blockIdx.x * 32, r0 = blockIdx.y * 32;
  int tx = threadIdx.x & 31, tg = threadIdx.x >> 5;
  for (int rr = tg; rr < 32; rr += 8) {
    int r = r0 + rr, c = c0 + tx;
    tile[rr][tx] = (r < rows && c < cols) ? in[(size_t)r * cols + c] : 0.f;
  }
  __syncthreads();
  for (int rr = tg; rr < 32; rr += 8) {
    int c = c0 + rr, r = r0 + tx;
    if (c < cols && r < rows) out[(size_t)c * rows + r] = tile[tx][rr];
  }
}

__global__ void k_softmax16(const float* __restrict__ X5, float* __restrict__ out, int rows) {
  int r = blockIdx.x * blockDim.x + threadIdx.x;
  if (r >= rows) return;
  float v[16];
  float m = -INFINITY;
#pragma unroll
  for (int c = 0; c < 16; ++c) { v[c] = X5[r * 16 + c]; m = fmaxf(m, v[c]); }
  float s = 0.f;
#pragma unroll
  for (int c = 0; c < 16; ++c) { v[c] = expf(v[c] - m); s += v[c]; }
  float inv = 1.f / s;
#pragma unroll
  for (int c = 0; c < 16; ++c) out[r * 16 + c] = v[c] * inv;
}

extern "C" void kernel_launch(void* const* d_in, const int* in_sizes, int n_in,
                              void* d_out, int out_size, void* d_ws, size_t ws_size,
                              hipStream_t stream) {
  const float* X     = (const float*)d_in[0];
  const float* Z     = (const float*)d_in[1];
  const float* adj_e = (const float*)d_in[2];
  const float* Tm    = (const float*)d_in[4];
  const int*   ei    = (const int*)d_in[5];
  const int* src = ei;
  const int* dst = ei + E2;
  const float* W1  = (const float*)d_in[6];
  const float* b1  = (const float*)d_in[7];
  const float* p2  = (const float*)d_in[8];
  const float* W2  = (const float*)d_in[9];
  const float* b2  = (const float*)d_in[10];
  const float* p3  = (const float*)d_in[11];
  const float* W3  = (const float*)d_in[12];
  const float* b3  = (const float*)d_in[13];
  const float* p32 = (const float*)d_in[14];
  const float* W32 = (const float*)d_in[15];
  const float* b32 = (const float*)d_in[16];
  const float* p4  = (const float*)d_in[17];
  const float* W4  = (const float*)d_in[18];
  const float* b4g = (const float*)d_in[19];
  const float* b4  = (const float*)d_in[20];
  const float* W5  = (const float*)d_in[21];
  const float* b5  = (const float*)d_in[22];

  char* wsb = (char*)d_ws;
  const bool big = ws_size >= (size_t)310 * 1024 * 1024;

  // ---- big layout (bytes) ----
  char* ApkB = wsb;                               // 3 x 72,384,512 = 217,153,536
  char* pAhi = wsb + 3 * APK_BYTES;               // 36,192,256 -> ends 253,345,792
  char* Bpk  = wsb + 253345792;                   // 770,048
  // gc4 overlay (edge state dead by then)
  char* mAhi = wsb;                               // 36,962,304
  char* Mpk  = wsb + 40000000;                    // 18,481,152
  char* gpk  = wsb + 60000000;                    // 770,048

  // small region at byte 255,000,000
  float* small = big ? (float*)(wsb + 255000000) : (float*)d_ws + 36000000;
  float* Xh    = small;
  float* xw    = small + 768000;
  float* Zh    = small + 1536000;
  float* HeW   = small + 1920000;
  float* Bc    = small + 2304000;
  float* g     = small + 2688000;
  float* svg   = small + 3072000;    // 3 x 3072
  float* se    = small + 3082000;    // 6016
  float* cmaxB = small + 3090000;    // 3 x 6016
  float* dinv  = small + 3110000;
  float* X5    = small + 3114000;    // 48000
  // fallback-only overlays
  float* A_fb     = (float*)d_ws;
  float* Tt_fb    = (float*)d_ws;
  float* mult1_fb = (float*)d_ws + 18000000;
  float* out  = (float*)d_out;

  auto gemm = [&](const float* Am, const float* Bm, const float* bias, const float* ksc,
                  float* C, int Mn, int Nn, int Kn, int relu, int splitk, int nt) {
    dim3 gr(cdiv(Nn, 64), cdiv(Mn, 64), splitk);
    if (splitk == 1) {
      if (nt) k_gemm64<1, 1><<<gr, 256, 0, stream>>>(Am, Bm, bias, ksc, C, Mn, Nn, Kn, relu);
      else    k_gemm64<1, 0><<<gr, 256, 0, stream>>>(Am, Bm, bias, ksc, C, Mn, Nn, Kn, relu);
    } else {
      if (nt) k_gemm64<4, 1><<<gr, 256, 0, stream>>>(Am, Bm, bias, ksc, C, Mn, Nn, Kn, relu);
      else    k_gemm64<4, 0><<<gr, 256, 0, stream>>>(Am, Bm, bias, ksc, C, Mn, Nn, Kn, relu);
    }
  };

  // ---- degrees / norms ----
  k_fill<<<cdiv(NN, 256), 256, 0, stream>>>(dinv, 0.f, NN);
  k_deg_count<<<cdiv(E2, 256), 256, 0, stream>>>(dst, dinv, E2);
  k_dinv<<<cdiv(NN, 256), 256, 0, stream>>>(dinv, NN);

  // ---- gc1 ----
  gemm(X, W1, nullptr, nullptr, xw, NN, H1, FV, 0, 1, 0);
  k_gcn_init<<<cdiv(NN * H1, 256), 256, 0, stream>>>(xw, dinv, b1, Xh, NN, 8);
  k_gcn_scatter<<<cdiv(E2 * H1, 256), 256, 0, stream>>>(xw, src, dst, dinv, Xh, E2, 8);
  k_relu<<<cdiv(NN * H1, 256), 256, 0, stream>>>(Xh, NN * H1);
  k_relu_copy<<<cdiv(MM * FE, 256), 256, 0, stream>>>(Z, Zh, MM * FE);

  const float* ep[3] = {p2, p3, p32};
  const float* eW[3] = {W2, W3, W32};
  const float* eb[3] = {b2, b3, b32};
  const int ntriE = CT_E * (CT_E + 1) / 2;   // 1128

  if (big) {
    // ---- pack unscaled T once; sv for all 3 edge layers (Xh is relu-invariant) ----
    dim3 gp(CT_E, KT_E);
    k_pack_edge<<<gp, 256, 0, stream>>>(Tm, nullptr, pAhi, nullptr, nullptr, 0, MM, NN, KT_E);
    for (int L = 0; L < 3; ++L)
      k_rowdot<<<cdiv(NN, 4), 256, 0, stream>>>(Xh, ep[L], svg + L * 3072, NN, H1);
    k_fill<<<cdiv(3 * 6016, 256), 256, 0, stream>>>(cmaxB, -INFINITY, 3 * 6016);

    // ---- merged 3-layer SYRK: An_L packs + colmax_L ----
    k_tsvt_sym<1, 12032><<<3 * ntriE, 256, 0, stream>>>(
        pAhi, svg, NN, 3072, adj_e, ApkB, cmaxB,
        MM, KT_E, CT_E, KT_A, ntriE, APK_BYTES, 6016);

    // ---- sequential Zh chain ----
    for (int L = 0; L < 3; ++L) {
      gemm(Zh, eW[L], nullptr, nullptr, HeW, MM, FE, FE, 0, 1, 0);
      k_prep_pack<<<KT_A, 256, 0, stream>>>(HeW, cmaxB + L * 6016, eb[L], Zh, Bpk, MM);
      dim3 gz(CT_E, 8);
      k_zh<<<gz, 256, 0, stream>>>(ApkB + (size_t)L * APK_BYTES, Bpk, Zh, MM, KT_A,
                                   cdiv(KT_A, 8));
      k_relu<<<cdiv(MM * FE, 256), 256, 0, stream>>>(Zh, MM * FE);
    }
  } else {
    for (int L = 0; L < 3; ++L) {
      k_rowdot<<<cdiv(NN, 4), 256, 0, stream>>>(Xh, ep[L], svg, NN, H1);
      gemm(Zh, eW[L], nullptr, nullptr, HeW, MM, FE, FE, 0, 1, 0);
      k_fill<<<cdiv(MM, 256), 256, 0, stream>>>(cmaxB, -INFINITY, MM);
      dim3 gm2(CT_E, CT_E);
      k_tsvt_cvt<1><<<gm2, 256, 0, stream>>>(Tm, svg, adj_e, A_fb, cmaxB, MM, NN);
      k_prep<<<cdiv(MM * FE, 256), 256, 0, stream>>>(HeW, cmaxB, eb[L], Bc, Zh, MM * FE);
      gemm(A_fb, Bc, nullptr, nullptr, Zh, MM, FE, MM, 0, 4, 1);
      k_relu<<<cdiv(MM * FE, 256), 256, 0, stream>>>(Zh, MM * FE);
    }
  }

  // ---- gc4 ----
  k_rowdot<<<cdiv(MM, 4), 256, 0, stream>>>(Zh, p4, se, MM, FE);
  gemm(Xh, W4, nullptr, nullptr, xw, NN, H2, H1, 0, 1, 0);
  k_gcn_init<<<cdiv(NN * H2, 256), 256, 0, stream>>>(xw, dinv, b4g, g, NN, 7);
  k_gcn_scatter<<<cdiv(E2 * H2, 256), 256, 0, stream>>>(xw, src, dst, dinv, g, E2, 7);
  if (big) {
    dim3 gp(CT_M, KT_M);
    k_pack_tt<<<gp, 256, 0, stream>>>(Tm, nullptr, mAhi, nullptr, 0, NN, MM, KT_M);
    const int ntriM = CT_M * (CT_M + 1) / 2;   // 300
    k_tsvt_sym<0, 24064><<<ntriM, 256, 0, stream>>>(
        mAhi, se, MM, 0, nullptr, Mpk, nullptr,
        NN, KT_M, CT_M, NPK_M, ntriM, 0, 0);
    k_pack_g<<<NPK_M, 256, 0, stream>>>(g, gpk, NN);
    k_fill_bias<<<cdiv(NN * H2, 256), 256, 0, stream>>>(Xh, b4, H2 - 1, NN * H2);
    dim3 gx(CT_M, 8);
    k_zh128<<<gx, 256, 0, stream>>>(Mpk, gpk, Xh, NN, NPK_M, cdiv(NPK_M, 8));
  } else {
    dim3 gt(cdiv(MM, 32), cdiv(NN, 32));
    k_transpose<<<gt, 256, 0, stream>>>(Tm, Tt_fb, NN, MM);
    dim3 gm1(cdiv(NN, 128), cdiv(NN, 128));
    k_tsvt_cvt<0><<<gm1, 256, 0, stream>>>(Tt_fb, se, nullptr, mult1_fb, nullptr, NN, MM);
    k_fill_bias<<<cdiv(NN * H2, 256), 256, 0, stream>>>(Xh, b4, H2 - 1, NN * H2);
    gemm(mult1_fb, g, nullptr, nullptr, Xh, NN, H2, NN, 0, 4, 0);
  }
  k_relu<<<cdiv(NN * H2, 256), 256, 0, stream>>>(Xh, NN * H2);

  // ---- gc5 + softmax ----
  gemm(Xh, W5, nullptr, nullptr, xw, NN, NC, H2, 0, 1, 0);
  k_gcn_init<<<cdiv(NN * NC, 256), 256, 0, stream>>>(xw, dinv, b5, X5, NN, 4);
  k_gcn_scatter<<<cdiv(E2 * NC, 256), 256, 0, stream>>>(xw, src, dst, dinv, X5, E2, 4);
  k_softmax16<<<cdiv(NN, 256), 256, 0, stream>>>(X5, out, NN);
}

// Round 15
// 1287.343 us; speedup vs baseline: 1.0091x; 1.0091x over previous
//
#include <hip/hip_runtime.h>
#include <cmath>
#include <cstddef>

#define NN 3000
#define MM 6000
#define FV 128
#define FE 64
#define H1 256
#define H2 128
#define NC 16
#define E2 12000

// pack-tile geometry: 128 cols x 32 k bf16 = 8192 B per tile
#define CT_E 47
#define KT_E 94
#define CT_M 24
#define KT_M 188
#define KT_A 188        // j-tiles (32-col) of A-pack
#define NPK_M 94        // j-tiles of mult1 pack
#define PKE_BYTES ((size_t)CT_E * KT_E * 8192)    // 36,192,256
#define PKM_BYTES ((size_t)CT_M * KT_M * 8192)    // 36,962,304
#define APK_BYTES ((size_t)CT_E * KT_A * 8192)    // 72,384,512

static inline int cdiv(int a, int b) { return (a + b - 1) / b; }

typedef __attribute__((ext_vector_type(8))) short short8;
typedef __attribute__((ext_vector_type(4))) float f32x4;

__device__ inline void atomicMaxFloat(float* addr, float v) {
  if (v >= 0.f) atomicMax((int*)addr, __float_as_int(v));
  else          atomicMin((unsigned int*)addr, __float_as_uint(v));
}

__device__ inline unsigned short b2h(float x) {   // RTN-even fp32->bf16
  unsigned int u = __float_as_uint(x);
  return (unsigned short)((u + 0x7FFFu + ((u >> 16) & 1u)) >> 16);
}

__device__ inline void bsplit(float x, unsigned short& h, unsigned short& l) {
  h = b2h(x);
  float hf = __uint_as_float(((unsigned int)h) << 16);
  l = b2h(x - hf);
}

__global__ void k_fill(float* p, float v, int n) {
  int i = blockIdx.x * blockDim.x + threadIdx.x;
  if (i < n) p[i] = v;
}

__global__ void k_fill_bias(float* p, const float* __restrict__ bias, int nmask, int total) {
  int i = blockIdx.x * blockDim.x + threadIdx.x;
  if (i < total) p[i] = bias[i & nmask];
}

__global__ void k_relu_copy(const float* __restrict__ in, float* __restrict__ out, int n) {
  int i = blockIdx.x * blockDim.x + threadIdx.x;
  if (i < n) out[i] = fmaxf(in[i], 0.f);
}

__global__ void k_relu(float* p, int n) {
  int i = blockIdx.x * blockDim.x + threadIdx.x;
  if (i < n) p[i] = fmaxf(p[i], 0.f);
}

__global__ void k_deg_count(const int* __restrict__ dst, float* deg, int ne) {
  int e = blockIdx.x * blockDim.x + threadIdx.x;
  if (e < ne) atomicAdd(&deg[dst[e]], 1.f);
}

__global__ void k_dinv(float* deg, int n) {
  int i = blockIdx.x * blockDim.x + threadIdx.x;
  if (i < n) deg[i] = rsqrtf(deg[i] + 1.0f);
}

__global__ void k_gcn_init(const float* __restrict__ xw, const float* __restrict__ dinv,
                           const float* __restrict__ bias, float* __restrict__ out,
                           int n, int flog2) {
  int idx = blockIdx.x * blockDim.x + threadIdx.x;
  int F = 1 << flog2;
  if (idx < n * F) {
    int i = idx >> flog2;
    int f = idx & (F - 1);
    float di = dinv[i];
    out[idx] = xw[idx] * di * di + bias[f];
  }
}

__global__ void k_gcn_scatter(const float* __restrict__ xw, const int* __restrict__ src,
                              const int* __restrict__ dst, const float* __restrict__ dinv,
                              float* __restrict__ out, int ne, int flog2) {
  int idx = blockIdx.x * blockDim.x + threadIdx.x;
  int F = 1 << flog2;
  if (idx < ne * F) {
    int e = idx >> flog2;
    int f = idx & (F - 1);
    int s = src[e], d = dst[e];
    atomicAdd(&out[d * F + f], xw[s * F + f] * dinv[s] * dinv[d]);
  }
}

__global__ void k_rowdot(const float* __restrict__ Xv, const float* __restrict__ p,
                         float* __restrict__ out, int rows, int K) {
  int row = blockIdx.x * 4 + (threadIdx.x >> 6);
  int lane = threadIdx.x & 63;
  if (row >= rows) return;
  float acc = 0.f;
  for (int k = lane; k < K; k += 64) acc += Xv[(size_t)row * K + k] * p[k];
  for (int off = 32; off > 0; off >>= 1) acc += __shfl_xor(acc, off);
  if (lane == 0) out[row] = acc;
}

// fallback-path: Bc = HeW/cmax ; Zh prefilled with bias (FE = 64)
__global__ void k_prep(const float* __restrict__ HeW, const float* __restrict__ cmax,
                       const float* __restrict__ bias,
                       float* __restrict__ Bc, float* __restrict__ Zh, int total) {
  int idx = blockIdx.x * blockDim.x + threadIdx.x;
  if (idx < total) {
    Bc[idx] = HeW[idx] / cmax[idx >> 6];
    Zh[idx] = bias[idx & 63];
  }
}

// big-path: Bpk tile = bf16(HeW/cmax) packed; Zh prefilled with bias. One block per kt.
__global__ void k_prep_pack(const float* __restrict__ HeW, const float* __restrict__ cmax,
                            const float* __restrict__ bias,
                            float* __restrict__ Zh, char* __restrict__ Bpk, int Kd) {
  int kt = blockIdx.x;
  int t = threadIdx.x;
  int f = t >> 2, g = t & 3;
  float bf = bias[f];
  unsigned short hv[8];
#pragma unroll
  for (int e = 0; e < 8; ++e) {
    int k = kt * 32 + g * 8 + e;
    float v = 0.f;
    if (k < Kd) {
      v = HeW[(size_t)k * 64 + f] / cmax[k];
      Zh[(size_t)k * 64 + f] = bf;
    }
    hv[e] = b2h(v);
  }
  uint4 H;
  H.x = (unsigned)hv[0] | ((unsigned)hv[1] << 16);
  H.y = (unsigned)hv[2] | ((unsigned)hv[3] << 16);
  H.z = (unsigned)hv[4] | ((unsigned)hv[5] << 16);
  H.w = (unsigned)hv[6] | ((unsigned)hv[7] << 16);
  *(uint4*)(Bpk + (size_t)kt * 4096 + f * 64 + ((g ^ ((f >> 1) & 3)) * 16)) = H;
}

// pack g [Kd][128] fp32 -> 128-col B tiles (8192 B per kt)
__global__ void k_pack_g(const float* __restrict__ g, char* __restrict__ gpk, int Kd) {
  int kt = blockIdx.x;
  int t = threadIdx.x;
#pragma unroll
  for (int it = 0; it < 2; ++it) {
    int idx = it * 256 + t;
    int f = idx >> 2, gsw = idx & 3;
    int gq = gsw ^ ((f >> 1) & 3);
    unsigned short hv[8];
#pragma unroll
    for (int e = 0; e < 8; ++e) {
      int k = kt * 32 + gq * 8 + e;
      float v = (k < Kd) ? g[(size_t)k * 128 + f] : 0.f;
      hv[e] = b2h(v);
    }
    uint4 H;
    H.x = (unsigned)hv[0] | ((unsigned)hv[1] << 16);
    H.y = (unsigned)hv[2] | ((unsigned)hv[3] << 16);
    H.z = (unsigned)hv[4] | ((unsigned)hv[5] << 16);
    H.w = (unsigned)hv[6] | ((unsigned)hv[7] << 16);
    *(uint4*)(gpk + (size_t)kt * 8192 + idx * 16) = H;
  }
}

// scale an existing bf16 pack by s[k]: dst(c,k) = bf16(src(c,k) * s[k]); optional cmax init
__global__ void k_scale_pack(const char* __restrict__ src, char* __restrict__ dst,
                             const float* __restrict__ s, float* __restrict__ cmax,
                             int nkt, int nk, int Md) {
  int ct = blockIdx.x, kt = blockIdx.y;
  size_t base = ((size_t)ct * nkt + kt) * 8192;
  int t = threadIdx.x;
  if (cmax && kt == 0 && t < 128) {
    int cc = ct * 128 + t;
    if (cc < Md) cmax[cc] = -INFINITY;
  }
#pragma unroll
  for (int it = 0; it < 2; ++it) {
    int idx = it * 256 + t;
    int c = idx >> 2, gsw = idx & 3;
    int g = gsw ^ ((c >> 1) & 3);
    uint4 H = *(const uint4*)(src + base + idx * 16);
    unsigned int hw[4] = {H.x, H.y, H.z, H.w};
    unsigned int ow[4];
#pragma unroll
    for (int p = 0; p < 4; ++p) {
      int k0 = kt * 32 + g * 8 + p * 2;
      float s0 = (k0 < nk) ? s[k0] : 0.f;
      float s1 = (k0 + 1 < nk) ? s[k0 + 1] : 0.f;
      float v0 = __uint_as_float((hw[p] & 0xFFFFu) << 16) * s0;
      float v1 = __uint_as_float((hw[p] >> 16) << 16) * s1;
      ow[p] = (unsigned)b2h(v0) | ((unsigned)b2h(v1) << 16);
    }
    uint4 O;
    O.x = ow[0]; O.y = ow[1]; O.z = ow[2]; O.w = ow[3];
    *(uint4*)(dst + base + idx * 16) = O;
  }
}

// read the unscaled pack ONCE, write 3 scaled packs (sv per layer); init 3 cmax arrays
__global__ void k_scale_pack3(const char* __restrict__ src,
                              char* __restrict__ d0, char* __restrict__ d1,
                              char* __restrict__ d2,
                              const float* __restrict__ svg, int nk,
                              float* __restrict__ cmaxB, int cs, int Md, int nkt) {
  int ct = blockIdx.x, kt = blockIdx.y;
  size_t base = ((size_t)ct * nkt + kt) * 8192;
  int t = threadIdx.x;
  if (kt == 0 && t < 128) {
    int cc = ct * 128 + t;
    if (cc < Md) {
      cmaxB[cc] = -INFINITY;
      cmaxB[cs + cc] = -INFINITY;
      cmaxB[2 * cs + cc] = -INFINITY;
    }
  }
  char* dsts[3] = {d0, d1, d2};
#pragma unroll
  for (int it = 0; it < 2; ++it) {
    int idx = it * 256 + t;
    int c = idx >> 2, gsw = idx & 3;
    int g = gsw ^ ((c >> 1) & 3);
    uint4 H = *(const uint4*)(src + base + idx * 16);
    unsigned int hw[4] = {H.x, H.y, H.z, H.w};
    float vf[8];
#pragma unroll
    for (int p = 0; p < 4; ++p) {
      vf[2 * p]     = __uint_as_float((hw[p] & 0xFFFFu) << 16);
      vf[2 * p + 1] = __uint_as_float((hw[p] >> 16) << 16);
    }
#pragma unroll
    for (int L = 0; L < 3; ++L) {
      const float* sv = svg + L * 3072;
      unsigned int ow[4];
#pragma unroll
      for (int p = 0; p < 4; ++p) {
        int k0 = kt * 32 + g * 8 + p * 2;
        float s0 = (k0 < nk) ? sv[k0] : 0.f;
        float s1 = (k0 + 1 < nk) ? sv[k0 + 1] : 0.f;
        ow[p] = (unsigned)b2h(vf[2 * p] * s0) | ((unsigned)b2h(vf[2 * p + 1] * s1) << 16);
      }
      uint4 O;
      O.x = ow[0]; O.y = ow[1]; O.z = ow[2]; O.w = ow[3];
      *(uint4*)(dsts[L] + base + idx * 16) = O;
    }
  }
}

// ===== pack kernels: bf16 tiles in the exact (swizzled) LDS image =====
// image: element (c,k) at byte  c*64 + ((k>>3) ^ ((c>>1)&3))*16 + (k&7)*2
__global__ void k_pack_edge(const float* __restrict__ T, const float* __restrict__ svp,
                            char* __restrict__ ph, char* __restrict__ pl,
                            float* __restrict__ cmax,
                            int scaled, int Md, int Kd, int nkt) {
  int ct = blockIdx.x, kt = blockIdx.y;
  size_t base = ((size_t)ct * nkt + kt) * 8192;
  int t = threadIdx.x;
  if (scaled && kt == 0 && t < 128) {
    int cc = ct * 128 + t;
    if (cc < Md) cmax[cc] = -INFINITY;
  }
#pragma unroll
  for (int it = 0; it < 2; ++it) {
    int tau = it * 256 + t;
    int c = tau & 127;
    int g = tau >> 7;
    int gc = ct * 128 + c;
    int off = c * 64 + ((g ^ ((c >> 1) & 3)) * 16);
    unsigned short hv[8], lv[8];
#pragma unroll
    for (int e = 0; e < 8; ++e) {
      int k = kt * 32 + g * 8 + e;
      float v = 0.f;
      if (k < Kd && gc < Md) {
        v = T[(size_t)k * Md + gc];
        if (scaled) v *= svp[k];
      }
      bsplit(v, hv[e], lv[e]);
    }
    uint4 H, L;
    H.x = (unsigned)hv[0] | ((unsigned)hv[1] << 16);
    H.y = (unsigned)hv[2] | ((unsigned)hv[3] << 16);
    H.z = (unsigned)hv[4] | ((unsigned)hv[5] << 16);
    H.w = (unsigned)hv[6] | ((unsigned)hv[7] << 16);
    *(uint4*)(ph + base + off) = H;
    if (pl) {
      L.x = (unsigned)lv[0] | ((unsigned)lv[1] << 16);
      L.y = (unsigned)lv[2] | ((unsigned)lv[3] << 16);
      L.z = (unsigned)lv[4] | ((unsigned)lv[5] << 16);
      L.w = (unsigned)lv[6] | ((unsigned)lv[7] << 16);
      *(uint4*)(pl + base + off) = L;
    }
  }
}

// transposed variant for mult1: value = T[node][edge], c over nodes, k over edges
__global__ void k_pack_tt(const float* __restrict__ T, const float* __restrict__ sep,
                          char* __restrict__ ph, char* __restrict__ pl,
                          int scaled, int Mt, int Kt, int nkt) {
  int ct = blockIdx.x, kt = blockIdx.y;
  size_t base = ((size_t)ct * nkt + kt) * 8192;
  int t = threadIdx.x;
#pragma unroll
  for (int it = 0; it < 2; ++it) {
    int tau = it * 256 + t;
    int c = tau >> 2;
    int g = tau & 3;
    int node = ct * 128 + c;
    int off = c * 64 + ((g ^ ((c >> 1) & 3)) * 16);
    unsigned short hv[8], lv[8];
#pragma unroll
    for (int e = 0; e < 8; ++e) {
      int k = kt * 32 + g * 8 + e;
      float v = 0.f;
      if (node < Mt && k < Kt) {
        v = T[(size_t)node * Kt + k];
        if (scaled) v *= sep[k];
      }
      bsplit(v, hv[e], lv[e]);
    }
    uint4 H, L;
    H.x = (unsigned)hv[0] | ((unsigned)hv[1] << 16);
    H.y = (unsigned)hv[2] | ((unsigned)hv[3] << 16);
    H.z = (unsigned)hv[4] | ((unsigned)hv[5] << 16);
    H.w = (unsigned)hv[6] | ((unsigned)hv[7] << 16);
    *(uint4*)(ph + base + off) = H;
    if (pl) {
      L.x = (unsigned)lv[0] | ((unsigned)lv[1] << 16);
      L.y = (unsigned)lv[2] | ((unsigned)lv[3] << 16);
      L.z = (unsigned)lv[4] | ((unsigned)lv[5] << 16);
      L.w = (unsigned)lv[6] | ((unsigned)lv[7] << 16);
      *(uint4*)(pl + base + off) = L;
    }
  }
}

// ===== SYRK-style MFMA kernel: Out = T^T diag(s) T (symmetric) — upper-tri 128x128 =====
// 4 waves of 64x64, 2-phase prefetch. LDS-transpose epilogue for coalesced mirror writes.
// EPI=1: diag->1, *adj (NT), bf16 pack writes, colmax atomics
// EPI=0: bf16 pack writes only (mult1 pack)
template <int EPI>
__global__ __launch_bounds__(256) void k_tsvt_sym(const char* __restrict__ pAh,
                                                  const char* __restrict__ pBh,
                                                  const float* __restrict__ adj,
                                                  char* __restrict__ Opk,
                                                  float* __restrict__ cmax,
                                                  int Md, int nkt, int nbt, int npk) {
  __shared__ __align__(16) char smem[32768];      // K-loop: 2 x (A|B); epilogue: m2^T bf16
  const int tid = threadIdx.x;
  const int lane = tid & 63;
  const int w = tid >> 6;          // 0..3
  const int wr = w >> 1;           // 0..1
  const int wc = w & 1;            // 0..1
  const int r16 = lane & 15;
  const int kb = lane >> 4;

  // bijective XCD remap on the linear upper-triangular index, then triangle decode
  int nwg = nbt * (nbt + 1) / 2;
  int orig = blockIdx.x;
  int q = nwg >> 3, r = nwg & 7;
  int xcd = orig & 7, pos = orig >> 3;
  int wgid = (xcd < r ? xcd * (q + 1) : r * (q + 1) + (xcd - r) * q) + pos;
  int bi = 0, rem = wgid;
  while (rem >= nbt - bi) { rem -= nbt - bi; ++bi; }
  int bj = bi + rem;

  const int i0 = bi * 128, j0 = bj * 128;

  const char* srcA = pAh + (size_t)bi * nkt * 8192;
  const char* srcB = pBh + (size_t)bj * nkt * 8192;
  const int c4 = w * 4;

  auto stage = [&](int kt, int buf) {
#pragma unroll
    for (int o = 0; o < 4; ++o) {
      int c = c4 + o;
      int sel = c >> 3, sub = c & 7;
      const char* s = (sel ? srcB : srcA) + (size_t)kt * 8192 + sub * 1024 + lane * 16;
      __builtin_amdgcn_global_load_lds(
          (const __attribute__((address_space(1))) void*)s,
          (__attribute__((address_space(3))) void*)(smem + buf * 16384 + c * 1024 + lane * 16),
          16, 0, 0);
    }
  };

  f32x4 acc[4][4];
#pragma unroll
  for (int a = 0; a < 4; ++a)
#pragma unroll
    for (int b = 0; b < 4; ++b) acc[a][b] = 0.f;

  stage(0, 0);
  __syncthreads();
  int cur = 0;
  for (int kt = 0; kt < nkt; ++kt) {
    if (kt + 1 < nkt) stage(kt + 1, cur ^ 1);
    const char* sA = smem + cur * 16384;
    const char* sB = sA + 8192;

    short8 bh[4];
#pragma unroll
    for (int nj = 0; nj < 4; ++nj) {
      int col = wc * 64 + nj * 16 + r16;
      bh[nj] = *(const short8*)(sB + col * 64 + ((kb ^ ((col >> 1) & 3)) * 16));
    }
#pragma unroll
    for (int mi = 0; mi < 4; ++mi) {
      int row = wr * 64 + mi * 16 + r16;
      short8 ah = *(const short8*)(sA + row * 64 + ((kb ^ ((row >> 1) & 3)) * 16));
#pragma unroll
      for (int nj = 0; nj < 4; ++nj)
        acc[mi][nj] = __builtin_amdgcn_mfma_f32_16x16x32_bf16(ah, bh[nj], acc[mi][nj], 0, 0, 0);
    }
    __syncthreads();
    cur ^= 1;
  }

  // ---- epilogue ----
  // Phase 0: raw m2 bf16 into LDS at (jl, il): byte jl*256 + ((il*2) ^ ((jl&7)<<4))
#pragma unroll
  for (int nj = 0; nj < 4; ++nj) {
    int jl = wc * 64 + nj * 16 + r16;
#pragma unroll
    for (int mi = 0; mi < 4; ++mi) {
      int ilb = wr * 64 + mi * 16 + kb * 4;
      f32x4 a = acc[mi][nj];
#pragma unroll
      for (int rr = 0; rr < 4; ++rr) {
        int il = ilb + rr;
        *(unsigned short*)(smem + jl * 256 + ((il * 2) ^ ((jl & 7) << 4))) = b2h(a[rr]);
      }
    }
  }

  // Phase 1: direct writes (i <= j), C/D layout col=lane&15, row=(lane>>4)*4+reg  [m89]
#pragma unroll
  for (int nj = 0; nj < 4; ++nj) {
    int j = j0 + wc * 64 + nj * 16 + r16;
    float cm = -INFINITY;
    bool jok = (j < Md);
#pragma unroll
    for (int mi = 0; mi < 4; ++mi) {
      int ib = i0 + wr * 64 + mi * 16 + kb * 4;
      f32x4 a = acc[mi][nj];
#pragma unroll
      for (int rr = 0; rr < 4; ++rr) {
        int i = ib + rr;
        if (i < Md && jok && i <= j) {
          float v = a[rr];
          if (EPI == 1) {
            if (i == j) v = 1.0f;
            v *= __builtin_nontemporal_load(&adj[(size_t)i * Md + j]);
            cm = fmaxf(cm, v);
          }
          *(unsigned short*)(Opk + ((size_t)(i >> 7) * npk + (j >> 5)) * 8192
              + (i & 127) * 64 + ((((j >> 3) & 3) ^ ((i >> 1) & 3)) * 16) + (j & 7) * 2)
              = b2h(v);
        }
      }
    }
    if (EPI == 1) {
      cm = fmaxf(cm, __shfl_xor(cm, 16));
      cm = fmaxf(cm, __shfl_xor(cm, 32));
      if (kb == 0 && jok) atomicMaxFloat(&cmax[j], cm);
    }
  }

  // Phase 2: mirror writes (j, i) with i < j — coalesced via the LDS transpose
  __syncthreads();
  {
    int ic = tid & 127;
    int i = i0 + ic;
    int rowpar = tid >> 7;       // 0 or 1
    bool iok = (i < Md);
    float lm = -INFINITY;
#pragma unroll 8
    for (int m = 0; m < 64; ++m) {
      int jr = m * 2 + rowpar;
      int j = j0 + jr;
      if (iok && j < Md && i < j) {
        unsigned short hv =
            *(unsigned short*)(smem + jr * 256 + ((ic * 2) ^ ((jr & 7) << 4)));
        float vm = __uint_as_float(((unsigned int)hv) << 16);
        if (EPI == 1) {
          float a2 = vm * __builtin_nontemporal_load(&adj[(size_t)j * Md + i]);
          *(unsigned short*)(Opk + ((size_t)(j >> 7) * npk + (i >> 5)) * 8192
              + (j & 127) * 64 + ((((i >> 3) & 3) ^ ((j >> 1) & 3)) * 16) + (i & 7) * 2)
              = b2h(a2);
          lm = fmaxf(lm, a2);
        } else {
          *(unsigned short*)(Opk + ((size_t)(j >> 7) * npk + (i >> 5)) * 8192
              + (j & 127) * 64 + ((((i >> 3) & 3) ^ ((j >> 1) & 3)) * 16) + (i & 7) * 2)
              = b2h(vm);
        }
      }
    }
    if (EPI == 1 && iok && lm > -INFINITY) atomicMaxFloat(&cmax[i], lm);
  }
}

// ===== MFMA kernel: Zh += Apack @ Bcpack (M x 64), split-K atomics =====
__global__ __launch_bounds__(256) void k_zh(const char* __restrict__ Apk,
                                            const char* __restrict__ Bpk,
                                            float* __restrict__ Zh,
                                            int Mn, int nktA, int zchunk) {
  __shared__ __align__(16) char smem[12288];      // A 8KB + B 4KB
  const int tid = threadIdx.x;
  const int lane = tid & 63;
  const int w = tid >> 6;
  const int r16 = lane & 15;
  const int kb = lane >> 4;
  const int bi = blockIdx.x;
  const int kt0 = blockIdx.y * zchunk;
  const int kt1 = min(nktA, kt0 + zchunk);
  const int i0 = bi * 128;

  f32x4 acc[2][4];
#pragma unroll
  for (int a = 0; a < 2; ++a)
#pragma unroll
    for (int b = 0; b < 4; ++b) acc[a][b] = 0.f;

  for (int kt = kt0; kt < kt1; ++kt) {
    const char* As = Apk + ((size_t)bi * nktA + kt) * 8192;
    const char* Bs = Bpk + (size_t)kt * 4096;
    __builtin_amdgcn_global_load_lds(
        (const __attribute__((address_space(1))) void*)(As + tid * 16),
        (__attribute__((address_space(3))) void*)(smem + tid * 16), 16, 0, 0);
    __builtin_amdgcn_global_load_lds(
        (const __attribute__((address_space(1))) void*)(As + 4096 + tid * 16),
        (__attribute__((address_space(3))) void*)(smem + 4096 + tid * 16), 16, 0, 0);
    __builtin_amdgcn_global_load_lds(
        (const __attribute__((address_space(1))) void*)(Bs + tid * 16),
        (__attribute__((address_space(3))) void*)(smem + 8192 + tid * 16), 16, 0, 0);
    __syncthreads();
    short8 bh[4];
#pragma unroll
    for (int nj = 0; nj < 4; ++nj) {
      int f = nj * 16 + r16;
      bh[nj] = *(const short8*)(smem + 8192 + f * 64 + ((kb ^ ((f >> 1) & 3)) * 16));
    }
#pragma unroll
    for (int mi = 0; mi < 2; ++mi) {
      int c = w * 32 + mi * 16 + r16;
      short8 ah = *(const short8*)(smem + c * 64 + ((kb ^ ((c >> 1) & 3)) * 16));
#pragma unroll
      for (int nj = 0; nj < 4; ++nj)
        acc[mi][nj] = __builtin_amdgcn_mfma_f32_16x16x32_bf16(ah, bh[nj], acc[mi][nj], 0, 0, 0);
    }
    __syncthreads();
  }
#pragma unroll
  for (int mi = 0; mi < 2; ++mi) {
    int ib = i0 + w * 32 + mi * 16 + kb * 4;
#pragma unroll
    for (int nj = 0; nj < 4; ++nj) {
      int f = nj * 16 + r16;
      f32x4 a = acc[mi][nj];
#pragma unroll
      for (int r = 0; r < 4; ++r) {
        int i = ib + r;
        if (i < Mn) atomicAdd(&Zh[(size_t)i * 64 + f], a[r]);
      }
    }
  }
}

// ===== MFMA kernel: C(+bias prefilled) += Apack @ Bpack128 (M x 128), split-K atomics =====
__global__ __launch_bounds__(256) void k_zh128(const char* __restrict__ Apk,
                                               const char* __restrict__ Bpk,
                                               float* __restrict__ C,
                                               int Mn, int nktA, int zchunk) {
  __shared__ __align__(16) char smem[16384];      // A 8KB + B 8KB
  const int tid = threadIdx.x;
  const int lane = tid & 63;
  const int w = tid >> 6;
  const int r16 = lane & 15;
  const int kb = lane >> 4;
  const int bi = blockIdx.x;
  const int kt0 = blockIdx.y * zchunk;
  const int kt1 = min(nktA, kt0 + zchunk);
  const int i0 = bi * 128;

  f32x4 acc[2][8];
#pragma unroll
  for (int a = 0; a < 2; ++a)
#pragma unroll
    for (int b = 0; b < 8; ++b) acc[a][b] = 0.f;

  for (int kt = kt0; kt < kt1; ++kt) {
    const char* As = Apk + ((size_t)bi * nktA + kt) * 8192;
    const char* Bs = Bpk + (size_t)kt * 8192;
#pragma unroll
    for (int o = 0; o < 4; ++o) {
      int idx = o * 256 + tid;
      const char* s = (idx < 512) ? (As + idx * 16) : (Bs + (idx - 512) * 16);
      __builtin_amdgcn_global_load_lds(
          (const __attribute__((address_space(1))) void*)s,
          (__attribute__((address_space(3))) void*)(smem + idx * 16), 16, 0, 0);
    }
    __syncthreads();
    short8 bh[8];
#pragma unroll
    for (int nj = 0; nj < 8; ++nj) {
      int f = nj * 16 + r16;
      bh[nj] = *(const short8*)(smem + 8192 + f * 64 + ((kb ^ ((f >> 1) & 3)) * 16));
    }
#pragma unroll
    for (int mi = 0; mi < 2; ++mi) {
      int c = w * 32 + mi * 16 + r16;
      short8 ah = *(const short8*)(smem + c * 64 + ((kb ^ ((c >> 1) & 3)) * 16));
#pragma unroll
      for (int nj = 0; nj < 8; ++nj)
        acc[mi][nj] = __builtin_amdgcn_mfma_f32_16x16x32_bf16(ah, bh[nj], acc[mi][nj], 0, 0, 0);
    }
    __syncthreads();
  }
#pragma unroll
  for (int mi = 0; mi < 2; ++mi) {
    int ib = i0 + w * 32 + mi * 16 + kb * 4;
#pragma unroll
    for (int nj = 0; nj < 8; ++nj) {
      int f = nj * 16 + r16;
      f32x4 a = acc[mi][nj];
#pragma unroll
      for (int r = 0; r < 4; ++r) {
        int i = ib + r;
        if (i < Mn) atomicAdd(&C[(size_t)i * 128 + f], a[r]);
      }
    }
  }
}

// ===== fallback MFMA kernel with in-kernel conversion (3-term) =====
template <int EPI>
__global__ __launch_bounds__(256) void k_tsvt_cvt(const float* __restrict__ Tmat,
                                                  const float* __restrict__ svp,
                                                  const float* __restrict__ adj,
                                                  float* __restrict__ Out,
                                                  float* __restrict__ cmax,
                                                  int Md, int Kd) {
  __shared__ __align__(16) unsigned short sAh[128 * 32];
  __shared__ __align__(16) unsigned short sAl[128 * 32];
  __shared__ __align__(16) unsigned short sBh[128 * 32];
  __shared__ __align__(16) unsigned short sBl[128 * 32];
  const int tid = threadIdx.x;
  const int lane = tid & 63;
  const int w = tid >> 6;
  const int wr = w >> 1, wc = w & 1;
  const int r16 = lane & 15;
  const int kb = lane >> 4;
  const int i0 = blockIdx.y * 128;
  const int j0 = blockIdx.x * 128;
  f32x4 acc[4][4];
#pragma unroll
  for (int a = 0; a < 4; ++a)
#pragma unroll
    for (int b = 0; b < 4; ++b) acc[a][b] = 0.f;
  for (int k0 = 0; k0 < Kd; k0 += 32) {
#pragma unroll
    for (int it = 0; it < 4; ++it) {
      int s = tid + it * 256;
      int ci = s & 127;
      int kq = s >> 7;
      int kk = kq * 4;
      int kbq = kq >> 1, half = kq & 1;
      int off = ci * 64 + (kbq ^ ((ci >> 1) & 3)) * 16 + half * 8;
      float va[4];
#pragma unroll
      for (int e = 0; e < 4; ++e) {
        int k = k0 + kk + e;
        int c = i0 + ci;
        va[e] = (k < Kd && c < Md) ? Tmat[(size_t)k * Md + c] : 0.f;
      }
      unsigned short h0, h1, h2, h3, l0, l1, l2, l3;
      bsplit(va[0], h0, l0); bsplit(va[1], h1, l1);
      bsplit(va[2], h2, l2); bsplit(va[3], h3, l3);
      uint2 hp, lp;
      hp.x = (unsigned)h0 | ((unsigned)h1 << 16); hp.y = (unsigned)h2 | ((unsigned)h3 << 16);
      lp.x = (unsigned)l0 | ((unsigned)l1 << 16); lp.y = (unsigned)l2 | ((unsigned)l3 << 16);
      *(uint2*)((char*)sAh + off) = hp;
      *(uint2*)((char*)sAl + off) = lp;
      float vb[4];
#pragma unroll
      for (int e = 0; e < 4; ++e) {
        int k = k0 + kk + e;
        int c = j0 + ci;
        float svv = (k < Kd) ? svp[k] : 0.f;
        vb[e] = (k < Kd && c < Md) ? Tmat[(size_t)k * Md + c] * svv : 0.f;
      }
      bsplit(vb[0], h0, l0); bsplit(vb[1], h1, l1);
      bsplit(vb[2], h2, l2); bsplit(vb[3], h3, l3);
      hp.x = (unsigned)h0 | ((unsigned)h1 << 16); hp.y = (unsigned)h2 | ((unsigned)h3 << 16);
      lp.x = (unsigned)l0 | ((unsigned)l1 << 16); lp.y = (unsigned)l2 | ((unsigned)l3 << 16);
      *(uint2*)((char*)sBh + off) = hp;
      *(uint2*)((char*)sBl + off) = lp;
    }
    __syncthreads();
    short8 bh[4], bl[4];
#pragma unroll
    for (int nj = 0; nj < 4; ++nj) {
      int col = wc * 64 + nj * 16 + r16;
      int off = col * 64 + ((kb ^ ((col >> 1) & 3)) * 16);
      bh[nj] = *(const short8*)((const char*)sBh + off);
      bl[nj] = *(const short8*)((const char*)sBl + off);
    }
#pragma unroll
    for (int mi = 0; mi < 4; ++mi) {
      int row = wr * 64 + mi * 16 + r16;
      int off = row * 64 + ((kb ^ ((row >> 1) & 3)) * 16);
      short8 ah = *(const short8*)((const char*)sAh + off);
      short8 al = *(const short8*)((const char*)sAl + off);
#pragma unroll
      for (int nj = 0; nj < 4; ++nj) {
        acc[mi][nj] = __builtin_amdgcn_mfma_f32_16x16x32_bf16(ah, bh[nj], acc[mi][nj], 0, 0, 0);
        acc[mi][nj] = __builtin_amdgcn_mfma_f32_16x16x32_bf16(ah, bl[nj], acc[mi][nj], 0, 0, 0);
        acc[mi][nj] = __builtin_amdgcn_mfma_f32_16x16x32_bf16(al, bh[nj], acc[mi][nj], 0, 0, 0);
      }
    }
    __syncthreads();
  }
#pragma unroll
  for (int nj = 0; nj < 4; ++nj) {
    int j = j0 + wc * 64 + nj * 16 + r16;
    float cm = -INFINITY;
#pragma unroll
    for (int mi = 0; mi < 4; ++mi) {
      int ib = i0 + wr * 64 + mi * 16 + kb * 4;
      f32x4 a = acc[mi][nj];
#pragma unroll
      for (int r = 0; r < 4; ++r) {
        int i = ib + r;
        if (i < Md && j < Md) {
          float v = a[r];
          if (EPI == 1) {
            if (i == j) v = 1.0f;
            v *= adj[(size_t)i * Md + j];
            Out[(size_t)i * Md + j] = v;
            cm = fmaxf(cm, v);
          } else {
            Out[(size_t)i * Md + j] = v;
          }
        }
      }
    }
    if (EPI == 1) {
      cm = fmaxf(cm, __shfl_xor(cm, 16));
      cm = fmaxf(cm, __shfl_xor(cm, 32));
      if (kb == 0 && j < Md) atomicMaxFloat(&cmax[j], cm);
    }
  }
}

// -------- generic 64x64 tiled fp32 GEMM ----
template <int SPLITK, int NT>
__global__ __launch_bounds__(256) void k_gemm64(const float* __restrict__ Am,
                                                const float* __restrict__ Bm,
                                                const float* __restrict__ bias,
                                                const float* __restrict__ kscale,
                                                float* __restrict__ C,
                                                int Mn, int Nn, int Kn, int relu) {
  __shared__ float As[16][68];
  __shared__ float Bs[16][68];
  int i0 = blockIdx.y * 64, j0 = blockIdx.x * 64;
  int kchunk = (Kn + SPLITK - 1) / SPLITK;
  int ks = blockIdx.z * kchunk;
  int ke = min(Kn, ks + kchunk);
  int tid = threadIdx.x;
  int tx = tid & 15, ty = tid >> 4;
  float acc[4][4] = {};
  for (int k0 = ks; k0 < ke; k0 += 16) {
#pragma unroll
    for (int l0 = 0; l0 < 1024; l0 += 256) {
      int l = l0 + tid;
      int i = l >> 4, k = l & 15;
      float v = 0.f;
      if (i0 + i < Mn && k0 + k < ke) {
        v = NT ? __builtin_nontemporal_load(&Am[(size_t)(i0 + i) * Kn + (k0 + k)])
               : Am[(size_t)(i0 + i) * Kn + (k0 + k)];
        if (kscale) v *= kscale[k0 + k];
      }
      As[k][i] = v;
    }
#pragma unroll
    for (int l0 = 0; l0 < 1024; l0 += 256) {
      int l = l0 + tid;
      int k = l >> 6, j = l & 63;
      float v = 0.f;
      if (k0 + k < ke && j0 + j < Nn) v = Bm[(size_t)(k0 + k) * Nn + (j0 + j)];
      Bs[k][j] = v;
    }
    __syncthreads();
#pragma unroll
    for (int k = 0; k < 16; ++k) {
      const float4 av = *(const float4*)&As[k][ty * 4];
      const float4 bv = *(const float4*)&Bs[k][tx * 4];
      float a_[4] = {av.x, av.y, av.z, av.w};
      float b_[4] = {bv.x, bv.y, bv.z, bv.w};
#pragma unroll
      for (int ri = 0; ri < 4; ++ri)
#pragma unroll
        for (int rj = 0; rj < 4; ++rj)
          acc[ri][rj] = fmaf(a_[ri], b_[rj], acc[ri][rj]);
    }
    __syncthreads();
  }
#pragma unroll
  for (int ri = 0; ri < 4; ++ri) {
    int i = i0 + ty * 4 + ri;
    if (i >= Mn) continue;
#pragma unroll
    for (int rj = 0; rj < 4; ++rj) {
      int j = j0 + tx * 4 + rj;
      if (j >= Nn) continue;
      float v = acc[ri][rj];
      if (SPLITK > 1) {
        atomicAdd(&C[(size_t)i * Nn + j], v);
      } else {
        if (bias) v += bias[j];
        if (relu) v = fmaxf(v, 0.f);
        C[(size_t)i * Nn + j] = v;
      }
    }
  }
}

__global__ void k_transpose(const float* __restrict__ in, float* __restrict__ out,
                            int rows, int cols) {
  __shared__ float tile[32][33];
  int c0 = blockIdx.x * 32, r0 = blockIdx.y * 32;
  int tx = threadIdx.x & 31, tg = threadIdx.x >> 5;
  for (int rr = tg; rr < 32; rr += 8) {
    int r = r0 + rr, c = c0 + tx;
    tile[rr][tx] = (r < rows && c < cols) ? in[(size_t)r * cols + c] : 0.f;
  }
  __syncthreads();
  for (int rr = tg; rr < 32; rr += 8) {
    int c = c0 + rr, r = r0 + tx;
    if (c < cols && r < rows) out[(size_t)c * rows + r] = tile[tx][rr];
  }
}

__global__ void k_softmax16(const float* __restrict__ X5, float* __restrict__ out, int rows) {
  int r = blockIdx.x * blockDim.x + threadIdx.x;
  if (r >= rows) return;
  float v[16];
  float m = -INFINITY;
#pragma unroll
  for (int c = 0; c < 16; ++c) { v[c] = X5[r * 16 + c]; m = fmaxf(m, v[c]); }
  float s = 0.f;
#pragma unroll
  for (int c = 0; c < 16; ++c) { v[c] = expf(v[c] - m); s += v[c]; }
  float inv = 1.f / s;
#pragma unroll
  for (int c = 0; c < 16; ++c) out[r * 16 + c] = v[c] * inv;
}

extern "C" void kernel_launch(void* const* d_in, const int* in_sizes, int n_in,
                              void* d_out, int out_size, void* d_ws, size_t ws_size,
                              hipStream_t stream) {
  const float* X     = (const float*)d_in[0];
  const float* Z     = (const float*)d_in[1];
  const float* adj_e = (const float*)d_in[2];
  const float* Tm    = (const float*)d_in[4];
  const int*   ei    = (const int*)d_in[5];
  const int* src = ei;
  const int* dst = ei + E2;
  const float* W1  = (const float*)d_in[6];
  const float* b1  = (const float*)d_in[7];
  const float* p2  = (const float*)d_in[8];
  const float* W2  = (const float*)d_in[9];
  const float* b2  = (const float*)d_in[10];
  const float* p3  = (const float*)d_in[11];
  const float* W3  = (const float*)d_in[12];
  const float* b3  = (const float*)d_in[13];
  const float* p32 = (const float*)d_in[14];
  const float* W32 = (const float*)d_in[15];
  const float* b32 = (const float*)d_in[16];
  const float* p4  = (const float*)d_in[17];
  const float* W4  = (const float*)d_in[18];
  const float* b4g = (const float*)d_in[19];
  const float* b4  = (const float*)d_in[20];
  const float* W5  = (const float*)d_in[21];
  const float* b5  = (const float*)d_in[22];

  char* wsb = (char*)d_ws;
  const bool big = ws_size >= (size_t)310 * 1024 * 1024;

  // ---- big layout (bytes) ----
  char* Apk   = wsb;                              // 72,384,512
  char* pAhi  = wsb + APK_BYTES;                  // 36,192,256 -> ends 108,576,768
  char* pBhi0 = wsb + 108576768;                  // 3 x 36,192,256
  char* pBhi1 = pBhi0 + PKE_BYTES;
  char* pBhi2 = pBhi1 + PKE_BYTES;                // ends 217,153,536
  char* Bpk   = wsb + 217153536;                  // 770,048
  // gc4 overlay (edge state dead by then)
  char* mAhi = wsb;                               // 36,962,304
  char* mBhi = mAhi + PKM_BYTES;                  // ends 73,924,608
  char* Mpk  = wsb + 80000000;                    // 18,481,152
  char* gpk  = wsb + 100000000;                   // 770,048

  // small region at byte 255,000,000
  float* small = big ? (float*)(wsb + 255000000) : (float*)d_ws + 36000000;
  float* Xh    = small;
  float* xw    = small + 768000;
  float* Zh    = small + 1536000;
  float* HeW   = small + 1920000;
  float* Bc    = small + 2304000;
  float* g     = small + 2688000;
  float* svg   = small + 3072000;    // 3 x 3072
  float* se    = small + 3082000;    // 6016
  float* cmaxB = small + 3090000;    // 3 x 6016
  float* dinv  = small + 3110000;
  float* X5    = small + 3114000;
  // fallback-only overlays
  float* A_fb     = (float*)d_ws;
  float* Tt_fb    = (float*)d_ws;
  float* mult1_fb = (float*)d_ws + 18000000;
  float* out  = (float*)d_out;

  auto gemm = [&](const float* Am, const float* Bm, const float* bias, const float* ksc,
                  float* C, int Mn, int Nn, int Kn, int relu, int splitk, int nt) {
    dim3 gr(cdiv(Nn, 64), cdiv(Mn, 64), splitk);
    if (splitk == 1) {
      if (nt) k_gemm64<1, 1><<<gr, 256, 0, stream>>>(Am, Bm, bias, ksc, C, Mn, Nn, Kn, relu);
      else    k_gemm64<1, 0><<<gr, 256, 0, stream>>>(Am, Bm, bias, ksc, C, Mn, Nn, Kn, relu);
    } else {
      if (nt) k_gemm64<4, 1><<<gr, 256, 0, stream>>>(Am, Bm, bias, ksc, C, Mn, Nn, Kn, relu);
      else    k_gemm64<4, 0><<<gr, 256, 0, stream>>>(Am, Bm, bias, ksc, C, Mn, Nn, Kn, relu);
    }
  };

  // ---- degrees / norms ----
  k_fill<<<cdiv(NN, 256), 256, 0, stream>>>(dinv, 0.f, NN);
  k_deg_count<<<cdiv(E2, 256), 256, 0, stream>>>(dst, dinv, E2);
  k_dinv<<<cdiv(NN, 256), 256, 0, stream>>>(dinv, NN);

  // ---- gc1 ----
  gemm(X, W1, nullptr, nullptr, xw, NN, H1, FV, 0, 1, 0);
  k_gcn_init<<<cdiv(NN * H1, 256), 256, 0, stream>>>(xw, dinv, b1, Xh, NN, 8);
  k_gcn_scatter<<<cdiv(E2 * H1, 256), 256, 0, stream>>>(xw, src, dst, dinv, Xh, E2, 8);
  k_relu<<<cdiv(NN * H1, 256), 256, 0, stream>>>(Xh, NN * H1);
  k_relu_copy<<<cdiv(MM * FE, 256), 256, 0, stream>>>(Z, Zh, MM * FE);

  const float* ep[3] = {p2, p3, p32};
  const float* eW[3] = {W2, W3, W32};
  const float* eb[3] = {b2, b3, b32};
  const int ntriE = CT_E * (CT_E + 1) / 2;   // 1128

  if (big) {
    // ---- pack unscaled T once; all 3 sv upfront (Xh is relu-invariant) ----
    dim3 gp(CT_E, KT_E);
    k_pack_edge<<<gp, 256, 0, stream>>>(Tm, nullptr, pAhi, nullptr, nullptr, 0, MM, NN, KT_E);
    for (int L = 0; L < 3; ++L)
      k_rowdot<<<cdiv(NN, 4), 256, 0, stream>>>(Xh, ep[L], svg + L * 3072, NN, H1);
    dim3 gs(CT_E, KT_E);
    k_scale_pack3<<<gs, 256, 0, stream>>>(pAhi, pBhi0, pBhi1, pBhi2, svg, NN,
                                          cmaxB, 6016, MM, KT_E);
    char* pB[3] = {pBhi0, pBhi1, pBhi2};

    // ---- per-layer: SYRK -> prep_pack -> zh -> relu ----
    for (int L = 0; L < 3; ++L) {
      gemm(Zh, eW[L], nullptr, nullptr, HeW, MM, FE, FE, 0, 1, 0);
      k_tsvt_sym<1><<<ntriE, 256, 0, stream>>>(pAhi, pB[L], adj_e, Apk,
                                               cmaxB + L * 6016, MM, KT_E, CT_E, KT_A);
      k_prep_pack<<<KT_A, 256, 0, stream>>>(HeW, cmaxB + L * 6016, eb[L], Zh, Bpk, MM);
      dim3 gz(CT_E, 8);
      k_zh<<<gz, 256, 0, stream>>>(Apk, Bpk, Zh, MM, KT_A, cdiv(KT_A, 8));
      k_relu<<<cdiv(MM * FE, 256), 256, 0, stream>>>(Zh, MM * FE);
    }
  } else {
    for (int L = 0; L < 3; ++L) {
      k_rowdot<<<cdiv(NN, 4), 256, 0, stream>>>(Xh, ep[L], svg, NN, H1);
      gemm(Zh, eW[L], nullptr, nullptr, HeW, MM, FE, FE, 0, 1, 0);
      k_fill<<<cdiv(MM, 256), 256, 0, stream>>>(cmaxB, -INFINITY, MM);
      dim3 gm2(CT_E, CT_E);
      k_tsvt_cvt<1><<<gm2, 256, 0, stream>>>(Tm, svg, adj_e, A_fb, cmaxB, MM, NN);
      k_prep<<<cdiv(MM * FE, 256), 256, 0, stream>>>(HeW, cmaxB, eb[L], Bc, Zh, MM * FE);
      gemm(A_fb, Bc, nullptr, nullptr, Zh, MM, FE, MM, 0, 4, 1);
      k_relu<<<cdiv(MM * FE, 256), 256, 0, stream>>>(Zh, MM * FE);
    }
  }

  // ---- gc4 ----
  k_rowdot<<<cdiv(MM, 4), 256, 0, stream>>>(Zh, p4, se, MM, FE);
  gemm(Xh, W4, nullptr, nullptr, xw, NN, H2, H1, 0, 1, 0);
  k_gcn_init<<<cdiv(NN * H2, 256), 256, 0, stream>>>(xw, dinv, b4g, g, NN, 7);
  k_gcn_scatter<<<cdiv(E2 * H2, 256), 256, 0, stream>>>(xw, src, dst, dinv, g, E2, 7);
  if (big) {
    dim3 gp(CT_M, KT_M);
    k_pack_tt<<<gp, 256, 0, stream>>>(Tm, nullptr, mAhi, nullptr, 0, NN, MM, KT_M);
    dim3 gs(CT_M, KT_M);
    k_scale_pack<<<gs, 256, 0, stream>>>(mAhi, mBhi, se, nullptr, KT_M, MM, 0);
    const int ntriM = CT_M * (CT_M + 1) / 2;   // 300
    k_tsvt_sym<0><<<ntriM, 256, 0, stream>>>(mAhi, mBhi, nullptr, Mpk, nullptr,
                                             NN, KT_M, CT_M, NPK_M);
    k_pack_g<<<NPK_M, 256, 0, stream>>>(g, gpk, NN);
    k_fill_bias<<<cdiv(NN * H2, 256), 256, 0, stream>>>(Xh, b4, H2 - 1, NN * H2);
    dim3 gx(CT_M, 8);
    k_zh128<<<gx, 256, 0, stream>>>(Mpk, gpk, Xh, NN, NPK_M, cdiv(NPK_M, 8));
  } else {
    dim3 gt(cdiv(MM, 32), cdiv(NN, 32));
    k_transpose<<<gt, 256, 0, stream>>>(Tm, Tt_fb, NN, MM);
    dim3 gm1(cdiv(NN, 128), cdiv(NN, 128));
    k_tsvt_cvt<0><<<gm1, 256, 0, stream>>>(Tt_fb, se, nullptr, mult1_fb, nullptr, NN, MM);
    k_fill_bias<<<cdiv(NN * H2, 256), 256, 0, stream>>>(Xh, b4, H2 - 1, NN * H2);
    gemm(mult1_fb, g, nullptr, nullptr, Xh, NN, H2, NN, 0, 4, 0);
  }
  k_relu<<<cdiv(NN * H2, 256), 256, 0, stream>>>(Xh, NN * H2);

  // ---- gc5 + softmax ----
  gemm(Xh, W5, nullptr, nullptr, xw, NN, NC, H2, 0, 1, 0);
  k_gcn_init<<<cdiv(NN * NC, 256), 256, 0, stream>>>(xw, dinv, b5, X5, NN, 4);
  k_gcn_scatter<<<cdiv(E2 * NC, 256), 256, 0, stream>>>(xw, src, dst, dinv, X5, E2, 4);
  k_softmax16<<<cdiv(NN, 256), 256, 0, stream>>>(X5, out, NN);
}

// Round 16
// 1232.372 us; speedup vs baseline: 1.0541x; 1.0446x over previous
//
#include <hip/hip_runtime.h>
#include <cmath>
#include <cstddef>

#define NN 3000
#define MM 6000
#define FV 128
#define FE 64
#define H1 256
#define H2 128
#define NC 16
#define E2 12000

// pack-tile geometry: 128 cols x 32 k bf16 = 8192 B per tile
#define CT_E 47
#define KT_E 94
#define CT_M 24
#define KT_M 188
#define KT_A 188        // j-tiles (32-col) of A-pack
#define NPK_M 94        // j-tiles of mult1 pack
#define PKA_BYTES ((size_t)48 * KT_E * 8192)
#define PKM_BYTES ((size_t)CT_M * KT_M * 8192)
#define APK_BYTES ((size_t)CT_E * KT_A * 8192)

static inline int cdiv(int a, int b) { return (a + b - 1) / b; }

typedef __attribute__((ext_vector_type(8))) short short8;
typedef __attribute__((ext_vector_type(4))) float f32x4;

__device__ inline void atomicMaxFloat(float* addr, float v) {
  if (v >= 0.f) atomicMax((int*)addr, __float_as_int(v));
  else          atomicMin((unsigned int*)addr, __float_as_uint(v));
}

__device__ inline unsigned short b2h(float x) {   // RTN-even fp32->bf16
  unsigned int u = __float_as_uint(x);
  return (unsigned short)((u + 0x7FFFu + ((u >> 16) & 1u)) >> 16);
}

__device__ inline void bsplit(float x, unsigned short& h, unsigned short& l) {
  h = b2h(x);
  float hf = __uint_as_float(((unsigned int)h) << 16);
  l = b2h(x - hf);
}

__global__ void k_fill(float* p, float v, int n) {
  int i = blockIdx.x * blockDim.x + threadIdx.x;
  if (i < n) p[i] = v;
}

__global__ void k_fill_bias(float* p, const float* __restrict__ bias, int nmask, int total) {
  int i = blockIdx.x * blockDim.x + threadIdx.x;
  if (i < total) p[i] = bias[i & nmask];
}

__global__ void k_relu_copy(const float* __restrict__ in, float* __restrict__ out, int n) {
  int i = blockIdx.x * blockDim.x + threadIdx.x;
  if (i < n) out[i] = fmaxf(in[i], 0.f);
}

__global__ void k_relu(float* p, int n) {
  int i = blockIdx.x * blockDim.x + threadIdx.x;
  if (i < n) p[i] = fmaxf(p[i], 0.f);
}

__global__ void k_deg_count(const int* __restrict__ dst, float* deg, int ne) {
  int e = blockIdx.x * blockDim.x + threadIdx.x;
  if (e < ne) atomicAdd(&deg[dst[e]], 1.f);
}

__global__ void k_dinv(float* deg, int n) {
  int i = blockIdx.x * blockDim.x + threadIdx.x;
  if (i < n) deg[i] = rsqrtf(deg[i] + 1.0f);
}

__global__ void k_gcn_init(const float* __restrict__ xw, const float* __restrict__ dinv,
                           const float* __restrict__ bias, float* __restrict__ out,
                           int n, int flog2) {
  int idx = blockIdx.x * blockDim.x + threadIdx.x;
  int F = 1 << flog2;
  if (idx < n * F) {
    int i = idx >> flog2;
    int f = idx & (F - 1);
    float di = dinv[i];
    out[idx] = xw[idx] * di * di + bias[f];
  }
}

__global__ void k_gcn_scatter(const float* __restrict__ xw, const int* __restrict__ src,
                              const int* __restrict__ dst, const float* __restrict__ dinv,
                              float* __restrict__ out, int ne, int flog2) {
  int idx = blockIdx.x * blockDim.x + threadIdx.x;
  int F = 1 << flog2;
  if (idx < ne * F) {
    int e = idx >> flog2;
    int f = idx & (F - 1);
    int s = src[e], d = dst[e];
    atomicAdd(&out[d * F + f], xw[s * F + f] * dinv[s] * dinv[d]);
  }
}

__global__ void k_rowdot(const float* __restrict__ Xv, const float* __restrict__ p,
                         float* __restrict__ out, int rows, int K) {
  int row = blockIdx.x * 4 + (threadIdx.x >> 6);
  int lane = threadIdx.x & 63;
  if (row >= rows) return;
  float acc = 0.f;
  for (int k = lane; k < K; k += 64) acc += Xv[(size_t)row * K + k] * p[k];
  for (int off = 32; off > 0; off >>= 1) acc += __shfl_xor(acc, off);
  if (lane == 0) out[row] = acc;
}

// fallback-path: Bc = HeW/cmax ; Zh prefilled with bias (FE = 64)
__global__ void k_prep(const float* __restrict__ HeW, const float* __restrict__ cmax,
                       const float* __restrict__ bias,
                       float* __restrict__ Bc, float* __restrict__ Zh, int total) {
  int idx = blockIdx.x * blockDim.x + threadIdx.x;
  if (idx < total) {
    Bc[idx] = HeW[idx] / cmax[idx >> 6];
    Zh[idx] = bias[idx & 63];
  }
}

// big-path: Bpk tile = bf16(HeW/cmax) packed; Zh prefilled with bias. One block per kt.
__global__ void k_prep_pack(const float* __restrict__ HeW, const float* __restrict__ cmax,
                            const float* __restrict__ bias,
                            float* __restrict__ Zh, char* __restrict__ Bpk, int Kd) {
  int kt = blockIdx.x;
  int t = threadIdx.x;
  int f = t >> 2, g = t & 3;
  float bf = bias[f];
  unsigned short hv[8];
#pragma unroll
  for (int e = 0; e < 8; ++e) {
    int k = kt * 32 + g * 8 + e;
    float v = 0.f;
    if (k < Kd) {
      v = HeW[(size_t)k * 64 + f] / cmax[k];
      Zh[(size_t)k * 64 + f] = bf;
    }
    hv[e] = b2h(v);
  }
  uint4 H;
  H.x = (unsigned)hv[0] | ((unsigned)hv[1] << 16);
  H.y = (unsigned)hv[2] | ((unsigned)hv[3] << 16);
  H.z = (unsigned)hv[4] | ((unsigned)hv[5] << 16);
  H.w = (unsigned)hv[6] | ((unsigned)hv[7] << 16);
  *(uint4*)(Bpk + (size_t)kt * 4096 + f * 64 + ((g ^ ((f >> 1) & 3)) * 16)) = H;
}

// pack g [Kd][128] fp32 -> 128-col B tiles (8192 B per kt)
__global__ void k_pack_g(const float* __restrict__ g, char* __restrict__ gpk, int Kd) {
  int kt = blockIdx.x;
  int t = threadIdx.x;
#pragma unroll
  for (int it = 0; it < 2; ++it) {
    int idx = it * 256 + t;
    int f = idx >> 2, gsw = idx & 3;
    int gq = gsw ^ ((f >> 1) & 3);
    unsigned short hv[8];
#pragma unroll
    for (int e = 0; e < 8; ++e) {
      int k = kt * 32 + gq * 8 + e;
      float v = (k < Kd) ? g[(size_t)k * 128 + f] : 0.f;
      hv[e] = b2h(v);
    }
    uint4 H;
    H.x = (unsigned)hv[0] | ((unsigned)hv[1] << 16);
    H.y = (unsigned)hv[2] | ((unsigned)hv[3] << 16);
    H.z = (unsigned)hv[4] | ((unsigned)hv[5] << 16);
    H.w = (unsigned)hv[6] | ((unsigned)hv[7] << 16);
    *(uint4*)(gpk + (size_t)kt * 8192 + idx * 16) = H;
  }
}

// scale an existing bf16 pack by s[k]: dst(c,k) = bf16(src(c,k) * s[k]); optional cmax init
__global__ void k_scale_pack(const char* __restrict__ src, char* __restrict__ dst,
                             const float* __restrict__ s, float* __restrict__ cmax,
                             int nkt, int nk, int Md) {
  int ct = blockIdx.x, kt = blockIdx.y;
  size_t base = ((size_t)ct * nkt + kt) * 8192;
  int t = threadIdx.x;
  if (cmax && kt == 0 && t < 128) {
    int cc = ct * 128 + t;
    if (cc < Md) cmax[cc] = -INFINITY;
  }
#pragma unroll
  for (int it = 0; it < 2; ++it) {
    int idx = it * 256 + t;
    int c = idx >> 2, gsw = idx & 3;
    int g = gsw ^ ((c >> 1) & 3);
    uint4 H = *(const uint4*)(src + base + idx * 16);
    unsigned int hw[4] = {H.x, H.y, H.z, H.w};
    unsigned int ow[4];
#pragma unroll
    for (int p = 0; p < 4; ++p) {
      int k0 = kt * 32 + g * 8 + p * 2;
      float s0 = (k0 < nk) ? s[k0] : 0.f;
      float s1 = (k0 + 1 < nk) ? s[k0 + 1] : 0.f;
      float v0 = __uint_as_float((hw[p] & 0xFFFFu) << 16) * s0;
      float v1 = __uint_as_float((hw[p] >> 16) << 16) * s1;
      ow[p] = (unsigned)b2h(v0) | ((unsigned)b2h(v1) << 16);
    }
    uint4 O;
    O.x = ow[0]; O.y = ow[1]; O.z = ow[2]; O.w = ow[3];
    *(uint4*)(dst + base + idx * 16) = O;
  }
}

// ===== pack kernels: bf16 tiles in the exact (swizzled) LDS image =====
// image: element (c,k) at byte  c*64 + ((k>>3) ^ ((c>>1)&3))*16 + (k&7)*2
__global__ void k_pack_edge(const float* __restrict__ T, const float* __restrict__ svp,
                            char* __restrict__ ph, char* __restrict__ pl,
                            float* __restrict__ cmax,
                            int scaled, int Md, int Kd, int nkt) {
  int ct = blockIdx.x, kt = blockIdx.y;
  size_t base = ((size_t)ct * nkt + kt) * 8192;
  int t = threadIdx.x;
  if (scaled && kt == 0 && t < 128) {
    int cc = ct * 128 + t;
    if (cc < Md) cmax[cc] = -INFINITY;
  }
#pragma unroll
  for (int it = 0; it < 2; ++it) {
    int tau = it * 256 + t;
    int c = tau & 127;
    int g = tau >> 7;
    int gc = ct * 128 + c;
    int off = c * 64 + ((g ^ ((c >> 1) & 3)) * 16);
    unsigned short hv[8], lv[8];
#pragma unroll
    for (int e = 0; e < 8; ++e) {
      int k = kt * 32 + g * 8 + e;
      float v = 0.f;
      if (k < Kd && gc < Md) {
        v = T[(size_t)k * Md + gc];
        if (scaled) v *= svp[k];
      }
      bsplit(v, hv[e], lv[e]);
    }
    uint4 H, L;
    H.x = (unsigned)hv[0] | ((unsigned)hv[1] << 16);
    H.y = (unsigned)hv[2] | ((unsigned)hv[3] << 16);
    H.z = (unsigned)hv[4] | ((unsigned)hv[5] << 16);
    H.w = (unsigned)hv[6] | ((unsigned)hv[7] << 16);
    *(uint4*)(ph + base + off) = H;
    if (pl) {
      L.x = (unsigned)lv[0] | ((unsigned)lv[1] << 16);
      L.y = (unsigned)lv[2] | ((unsigned)lv[3] << 16);
      L.z = (unsigned)lv[4] | ((unsigned)lv[5] << 16);
      L.w = (unsigned)lv[6] | ((unsigned)lv[7] << 16);
      *(uint4*)(pl + base + off) = L;
    }
  }
}

// transposed variant for mult1: value = T[node][edge], c over nodes, k over edges
__global__ void k_pack_tt(const float* __restrict__ T, const float* __restrict__ sep,
                          char* __restrict__ ph, char* __restrict__ pl,
                          int scaled, int Mt, int Kt, int nkt) {
  int ct = blockIdx.x, kt = blockIdx.y;
  size_t base = ((size_t)ct * nkt + kt) * 8192;
  int t = threadIdx.x;
#pragma unroll
  for (int it = 0; it < 2; ++it) {
    int tau = it * 256 + t;
    int c = tau >> 2;
    int g = tau & 3;
    int node = ct * 128 + c;
    int off = c * 64 + ((g ^ ((c >> 1) & 3)) * 16);
    unsigned short hv[8], lv[8];
#pragma unroll
    for (int e = 0; e < 8; ++e) {
      int k = kt * 32 + g * 8 + e;
      float v = 0.f;
      if (node < Mt && k < Kt) {
        v = T[(size_t)node * Kt + k];
        if (scaled) v *= sep[k];
      }
      bsplit(v, hv[e], lv[e]);
    }
    uint4 H, L;
    H.x = (unsigned)hv[0] | ((unsigned)hv[1] << 16);
    H.y = (unsigned)hv[2] | ((unsigned)hv[3] << 16);
    H.z = (unsigned)hv[4] | ((unsigned)hv[5] << 16);
    H.w = (unsigned)hv[6] | ((unsigned)hv[7] << 16);
    *(uint4*)(ph + base + off) = H;
    if (pl) {
      L.x = (unsigned)lv[0] | ((unsigned)lv[1] << 16);
      L.y = (unsigned)lv[2] | ((unsigned)lv[3] << 16);
      L.z = (unsigned)lv[4] | ((unsigned)lv[5] << 16);
      L.w = (unsigned)lv[6] | ((unsigned)lv[7] << 16);
      *(uint4*)(pl + base + off) = L;
    }
  }
}

// ===== SYRK-style MFMA kernel: Out = T^T diag(s) T (symmetric) — upper-tri 128x128 =====
// 4 waves of 64x64, 2-phase prefetch. LDS-transpose epilogue for coalesced mirror writes.
// EPI=1: diag->1, *adj (NT), bf16 pack writes, colmax atomics
// EPI=0: bf16 pack writes only (mult1 pack)
template <int EPI>
__global__ __launch_bounds__(256) void k_tsvt_sym(const char* __restrict__ pAh,
                                                  const char* __restrict__ pBh,
                                                  const float* __restrict__ adj,
                                                  char* __restrict__ Opk,
                                                  float* __restrict__ cmax,
                                                  int Md, int nkt, int nbt, int npk) {
  __shared__ __align__(16) char smem[32768];      // K-loop: 2 x (A|B); epilogue: m2^T bf16
  const int tid = threadIdx.x;
  const int lane = tid & 63;
  const int w = tid >> 6;          // 0..3
  const int wr = w >> 1;           // 0..1
  const int wc = w & 1;            // 0..1
  const int r16 = lane & 15;
  const int kb = lane >> 4;

  // bijective XCD remap on the linear upper-triangular index, then triangle decode
  int nwg = nbt * (nbt + 1) / 2;
  int orig = blockIdx.x;
  int q = nwg >> 3, r = nwg & 7;
  int xcd = orig & 7, pos = orig >> 3;
  int wgid = (xcd < r ? xcd * (q + 1) : r * (q + 1) + (xcd - r) * q) + pos;
  int bi = 0, rem = wgid;
  while (rem >= nbt - bi) { rem -= nbt - bi; ++bi; }
  int bj = bi + rem;

  const int i0 = bi * 128, j0 = bj * 128;

  const char* srcA = pAh + (size_t)bi * nkt * 8192;
  const char* srcB = pBh + (size_t)bj * nkt * 8192;
  const int c4 = w * 4;

  auto stage = [&](int kt, int buf) {
#pragma unroll
    for (int o = 0; o < 4; ++o) {
      int c = c4 + o;
      int sel = c >> 3, sub = c & 7;
      const char* s = (sel ? srcB : srcA) + (size_t)kt * 8192 + sub * 1024 + lane * 16;
      __builtin_amdgcn_global_load_lds(
          (const __attribute__((address_space(1))) void*)s,
          (__attribute__((address_space(3))) void*)(smem + buf * 16384 + c * 1024 + lane * 16),
          16, 0, 0);
    }
  };

  f32x4 acc[4][4];
#pragma unroll
  for (int a = 0; a < 4; ++a)
#pragma unroll
    for (int b = 0; b < 4; ++b) acc[a][b] = 0.f;

  stage(0, 0);
  __syncthreads();
  int cur = 0;
  for (int kt = 0; kt < nkt; ++kt) {
    if (kt + 1 < nkt) stage(kt + 1, cur ^ 1);
    const char* sA = smem + cur * 16384;
    const char* sB = sA + 8192;

    short8 bh[4];
#pragma unroll
    for (int nj = 0; nj < 4; ++nj) {
      int col = wc * 64 + nj * 16 + r16;
      bh[nj] = *(const short8*)(sB + col * 64 + ((kb ^ ((col >> 1) & 3)) * 16));
    }
#pragma unroll
    for (int mi = 0; mi < 4; ++mi) {
      int row = wr * 64 + mi * 16 + r16;
      short8 ah = *(const short8*)(sA + row * 64 + ((kb ^ ((row >> 1) & 3)) * 16));
#pragma unroll
      for (int nj = 0; nj < 4; ++nj)
        acc[mi][nj] = __builtin_amdgcn_mfma_f32_16x16x32_bf16(ah, bh[nj], acc[mi][nj], 0, 0, 0);
    }
    __syncthreads();
    cur ^= 1;
  }

  // ---- epilogue ----
  // Phase 0: raw m2 bf16 into LDS at (jl, il): byte jl*256 + ((il*2) ^ ((jl&7)<<4))
#pragma unroll
  for (int nj = 0; nj < 4; ++nj) {
    int jl = wc * 64 + nj * 16 + r16;
#pragma unroll
    for (int mi = 0; mi < 4; ++mi) {
      int ilb = wr * 64 + mi * 16 + kb * 4;
      f32x4 a = acc[mi][nj];
#pragma unroll
      for (int rr = 0; rr < 4; ++rr) {
        int il = ilb + rr;
        *(unsigned short*)(smem + jl * 256 + ((il * 2) ^ ((jl & 7) << 4))) = b2h(a[rr]);
      }
    }
  }

  // Phase 1: direct writes (i <= j), C/D layout col=lane&15, row=(lane>>4)*4+reg  [m89]
#pragma unroll
  for (int nj = 0; nj < 4; ++nj) {
    int j = j0 + wc * 64 + nj * 16 + r16;
    float cm = -INFINITY;
    bool jok = (j < Md);
#pragma unroll
    for (int mi = 0; mi < 4; ++mi) {
      int ib = i0 + wr * 64 + mi * 16 + kb * 4;
      f32x4 a = acc[mi][nj];
#pragma unroll
      for (int rr = 0; rr < 4; ++rr) {
        int i = ib + rr;
        if (i < Md && jok && i <= j) {
          float v = a[rr];
          if (EPI == 1) {
            if (i == j) v = 1.0f;
            v *= __builtin_nontemporal_load(&adj[(size_t)i * Md + j]);
            cm = fmaxf(cm, v);
          }
          *(unsigned short*)(Opk + ((size_t)(i >> 7) * npk + (j >> 5)) * 8192
              + (i & 127) * 64 + ((((j >> 3) & 3) ^ ((i >> 1) & 3)) * 16) + (j & 7) * 2)
              = b2h(v);
        }
      }
    }
    if (EPI == 1) {
      cm = fmaxf(cm, __shfl_xor(cm, 16));
      cm = fmaxf(cm, __shfl_xor(cm, 32));
      if (kb == 0 && jok) atomicMaxFloat(&cmax[j], cm);
    }
  }

  // Phase 2: mirror writes (j, i) with i < j — coalesced via the LDS transpose
  __syncthreads();
  {
    int ic = tid & 127;
    int i = i0 + ic;
    int rowpar = tid >> 7;       // 0 or 1
    bool iok = (i < Md);
    float lm = -INFINITY;
#pragma unroll 8
    for (int m = 0; m < 64; ++m) {
      int jr = m * 2 + rowpar;
      int j = j0 + jr;
      if (iok && j < Md && i < j) {
        unsigned short hv =
            *(unsigned short*)(smem + jr * 256 + ((ic * 2) ^ ((jr & 7) << 4)));
        float vm = __uint_as_float(((unsigned int)hv) << 16);
        if (EPI == 1) {
          float a2 = vm * __builtin_nontemporal_load(&adj[(size_t)j * Md + i]);
          *(unsigned short*)(Opk + ((size_t)(j >> 7) * npk + (i >> 5)) * 8192
              + (j & 127) * 64 + ((((i >> 3) & 3) ^ ((j >> 1) & 3)) * 16) + (i & 7) * 2)
              = b2h(a2);
          lm = fmaxf(lm, a2);
        } else {
          *(unsigned short*)(Opk + ((size_t)(j >> 7) * npk + (i >> 5)) * 8192
              + (j & 127) * 64 + ((((i >> 3) & 3) ^ ((j >> 1) & 3)) * 16) + (i & 7) * 2)
              = b2h(vm);
        }
      }
    }
    if (EPI == 1 && iok && lm > -INFINITY) atomicMaxFloat(&cmax[i], lm);
  }
}

// ===== MFMA kernel: Zh += Apack @ Bcpack (M x 64), split-K atomics =====
__global__ __launch_bounds__(256) void k_zh(const char* __restrict__ Apk,
                                            const char* __restrict__ Bpk,
                                            float* __restrict__ Zh,
                                            int Mn, int nktA, int zchunk) {
  __shared__ __align__(16) char smem[12288];      // A 8KB + B 4KB
  const int tid = threadIdx.x;
  const int lane = tid & 63;
  const int w = tid >> 6;
  const int r16 = lane & 15;
  const int kb = lane >> 4;
  const int bi = blockIdx.x;
  const int kt0 = blockIdx.y * zchunk;
  const int kt1 = min(nktA, kt0 + zchunk);
  const int i0 = bi * 128;

  f32x4 acc[2][4];
#pragma unroll
  for (int a = 0; a < 2; ++a)
#pragma unroll
    for (int b = 0; b < 4; ++b) acc[a][b] = 0.f;

  for (int kt = kt0; kt < kt1; ++kt) {
    const char* As = Apk + ((size_t)bi * nktA + kt) * 8192;
    const char* Bs = Bpk + (size_t)kt * 4096;
    __builtin_amdgcn_global_load_lds(
        (const __attribute__((address_space(1))) void*)(As + tid * 16),
        (__attribute__((address_space(3))) void*)(smem + tid * 16), 16, 0, 0);
    __builtin_amdgcn_global_load_lds(
        (const __attribute__((address_space(1))) void*)(As + 4096 + tid * 16),
        (__attribute__((address_space(3))) void*)(smem + 4096 + tid * 16), 16, 0, 0);
    __builtin_amdgcn_global_load_lds(
        (const __attribute__((address_space(1))) void*)(Bs + tid * 16),
        (__attribute__((address_space(3))) void*)(smem + 8192 + tid * 16), 16, 0, 0);
    __syncthreads();
    short8 bh[4];
#pragma unroll
    for (int nj = 0; nj < 4; ++nj) {
      int f = nj * 16 + r16;
      bh[nj] = *(const short8*)(smem + 8192 + f * 64 + ((kb ^ ((f >> 1) & 3)) * 16));
    }
#pragma unroll
    for (int mi = 0; mi < 2; ++mi) {
      int c = w * 32 + mi * 16 + r16;
      short8 ah = *(const short8*)(smem + c * 64 + ((kb ^ ((c >> 1) & 3)) * 16));
#pragma unroll
      for (int nj = 0; nj < 4; ++nj)
        acc[mi][nj] = __builtin_amdgcn_mfma_f32_16x16x32_bf16(ah, bh[nj], acc[mi][nj], 0, 0, 0);
    }
    __syncthreads();
  }
#pragma unroll
  for (int mi = 0; mi < 2; ++mi) {
    int ib = i0 + w * 32 + mi * 16 + kb * 4;
#pragma unroll
    for (int nj = 0; nj < 4; ++nj) {
      int f = nj * 16 + r16;
      f32x4 a = acc[mi][nj];
#pragma unroll
      for (int r = 0; r < 4; ++r) {
        int i = ib + r;
        if (i < Mn) atomicAdd(&Zh[(size_t)i * 64 + f], a[r]);
      }
    }
  }
}

// ===== MFMA kernel: C(+bias prefilled) += Apack @ Bpack128 (M x 128), split-K atomics =====
__global__ __launch_bounds__(256) void k_zh128(const char* __restrict__ Apk,
                                               const char* __restrict__ Bpk,
                                               float* __restrict__ C,
                                               int Mn, int nktA, int zchunk) {
  __shared__ __align__(16) char smem[16384];      // A 8KB + B 8KB
  const int tid = threadIdx.x;
  const int lane = tid & 63;
  const int w = tid >> 6;
  const int r16 = lane & 15;
  const int kb = lane >> 4;
  const int bi = blockIdx.x;
  const int kt0 = blockIdx.y * zchunk;
  const int kt1 = min(nktA, kt0 + zchunk);
  const int i0 = bi * 128;

  f32x4 acc[2][8];
#pragma unroll
  for (int a = 0; a < 2; ++a)
#pragma unroll
    for (int b = 0; b < 8; ++b) acc[a][b] = 0.f;

  for (int kt = kt0; kt < kt1; ++kt) {
    const char* As = Apk + ((size_t)bi * nktA + kt) * 8192;
    const char* Bs = Bpk + (size_t)kt * 8192;
#pragma unroll
    for (int o = 0; o < 4; ++o) {
      int idx = o * 256 + tid;
      const char* s = (idx < 512) ? (As + idx * 16) : (Bs + (idx - 512) * 16);
      __builtin_amdgcn_global_load_lds(
          (const __attribute__((address_space(1))) void*)s,
          (__attribute__((address_space(3))) void*)(smem + idx * 16), 16, 0, 0);
    }
    __syncthreads();
    short8 bh[8];
#pragma unroll
    for (int nj = 0; nj < 8; ++nj) {
      int f = nj * 16 + r16;
      bh[nj] = *(const short8*)(smem + 8192 + f * 64 + ((kb ^ ((f >> 1) & 3)) * 16));
    }
#pragma unroll
    for (int mi = 0; mi < 2; ++mi) {
      int c = w * 32 + mi * 16 + r16;
      short8 ah = *(const short8*)(smem + c * 64 + ((kb ^ ((c >> 1) & 3)) * 16));
#pragma unroll
      for (int nj = 0; nj < 8; ++nj)
        acc[mi][nj] = __builtin_amdgcn_mfma_f32_16x16x32_bf16(ah, bh[nj], acc[mi][nj], 0, 0, 0);
    }
    __syncthreads();
  }
#pragma unroll
  for (int mi = 0; mi < 2; ++mi) {
    int ib = i0 + w * 32 + mi * 16 + kb * 4;
#pragma unroll
    for (int nj = 0; nj < 8; ++nj) {
      int f = nj * 16 + r16;
      f32x4 a = acc[mi][nj];
#pragma unroll
      for (int r = 0; r < 4; ++r) {
        int i = ib + r;
        if (i < Mn) atomicAdd(&C[(size_t)i * 128 + f], a[r]);
      }
    }
  }
}

// ===== fallback MFMA kernel with in-kernel conversion (3-term) =====
template <int EPI>
__global__ __launch_bounds__(256) void k_tsvt_cvt(const float* __restrict__ Tmat,
                                                  const float* __restrict__ svp,
                                                  const float* __restrict__ adj,
                                                  float* __restrict__ Out,
                                                  float* __restrict__ cmax,
                                                  int Md, int Kd) {
  __shared__ __align__(16) unsigned short sAh[128 * 32];
  __shared__ __align__(16) unsigned short sAl[128 * 32];
  __shared__ __align__(16) unsigned short sBh[128 * 32];
  __shared__ __align__(16) unsigned short sBl[128 * 32];
  const int tid = threadIdx.x;
  const int lane = tid & 63;
  const int w = tid >> 6;
  const int wr = w >> 1, wc = w & 1;
  const int r16 = lane & 15;
  const int kb = lane >> 4;
  const int i0 = blockIdx.y * 128;
  const int j0 = blockIdx.x * 128;
  f32x4 acc[4][4];
#pragma unroll
  for (int a = 0; a < 4; ++a)
#pragma unroll
    for (int b = 0; b < 4; ++b) acc[a][b] = 0.f;
  for (int k0 = 0; k0 < Kd; k0 += 32) {
#pragma unroll
    for (int it = 0; it < 4; ++it) {
      int s = tid + it * 256;
      int ci = s & 127;
      int kq = s >> 7;
      int kk = kq * 4;
      int kbq = kq >> 1, half = kq & 1;
      int off = ci * 64 + (kbq ^ ((ci >> 1) & 3)) * 16 + half * 8;
      float va[4];
#pragma unroll
      for (int e = 0; e < 4; ++e) {
        int k = k0 + kk + e;
        int c = i0 + ci;
        va[e] = (k < Kd && c < Md) ? Tmat[(size_t)k * Md + c] : 0.f;
      }
      unsigned short h0, h1, h2, h3, l0, l1, l2, l3;
      bsplit(va[0], h0, l0); bsplit(va[1], h1, l1);
      bsplit(va[2], h2, l2); bsplit(va[3], h3, l3);
      uint2 hp, lp;
      hp.x = (unsigned)h0 | ((unsigned)h1 << 16); hp.y = (unsigned)h2 | ((unsigned)h3 << 16);
      lp.x = (unsigned)l0 | ((unsigned)l1 << 16); lp.y = (unsigned)l2 | ((unsigned)l3 << 16);
      *(uint2*)((char*)sAh + off) = hp;
      *(uint2*)((char*)sAl + off) = lp;
      float vb[4];
#pragma unroll
      for (int e = 0; e < 4; ++e) {
        int k = k0 + kk + e;
        int c = j0 + ci;
        float svv = (k < Kd) ? svp[k] : 0.f;
        vb[e] = (k < Kd && c < Md) ? Tmat[(size_t)k * Md + c] * svv : 0.f;
      }
      bsplit(vb[0], h0, l0); bsplit(vb[1], h1, l1);
      bsplit(vb[2], h2, l2); bsplit(vb[3], h3, l3);
      hp.x = (unsigned)h0 | ((unsigned)h1 << 16); hp.y = (unsigned)h2 | ((unsigned)h3 << 16);
      lp.x = (unsigned)l0 | ((unsigned)l1 << 16); lp.y = (unsigned)l2 | ((unsigned)l3 << 16);
      *(uint2*)((char*)sBh + off) = hp;
      *(uint2*)((char*)sBl + off) = lp;
    }
    __syncthreads();
    short8 bh[4], bl[4];
#pragma unroll
    for (int nj = 0; nj < 4; ++nj) {
      int col = wc * 64 + nj * 16 + r16;
      int off = col * 64 + ((kb ^ ((col >> 1) & 3)) * 16);
      bh[nj] = *(const short8*)((const char*)sBh + off);
      bl[nj] = *(const short8*)((const char*)sBl + off);
    }
#pragma unroll
    for (int mi = 0; mi < 4; ++mi) {
      int row = wr * 64 + mi * 16 + r16;
      int off = row * 64 + ((kb ^ ((row >> 1) & 3)) * 16);
      short8 ah = *(const short8*)((const char*)sAh + off);
      short8 al = *(const short8*)((const char*)sAl + off);
#pragma unroll
      for (int nj = 0; nj < 4; ++nj) {
        acc[mi][nj] = __builtin_amdgcn_mfma_f32_16x16x32_bf16(ah, bh[nj], acc[mi][nj], 0, 0, 0);
        acc[mi][nj] = __builtin_amdgcn_mfma_f32_16x16x32_bf16(ah, bl[nj], acc[mi][nj], 0, 0, 0);
        acc[mi][nj] = __builtin_amdgcn_mfma_f32_16x16x32_bf16(al, bh[nj], acc[mi][nj], 0, 0, 0);
      }
    }
    __syncthreads();
  }
#pragma unroll
  for (int nj = 0; nj < 4; ++nj) {
    int j = j0 + wc * 64 + nj * 16 + r16;
    float cm = -INFINITY;
#pragma unroll
    for (int mi = 0; mi < 4; ++mi) {
      int ib = i0 + wr * 64 + mi * 16 + kb * 4;
      f32x4 a = acc[mi][nj];
#pragma unroll
      for (int r = 0; r < 4; ++r) {
        int i = ib + r;
        if (i < Md && j < Md) {
          float v = a[r];
          if (EPI == 1) {
            if (i == j) v = 1.0f;
            v *= adj[(size_t)i * Md + j];
            Out[(size_t)i * Md + j] = v;
            cm = fmaxf(cm, v);
          } else {
            Out[(size_t)i * Md + j] = v;
          }
        }
      }
    }
    if (EPI == 1) {
      cm = fmaxf(cm, __shfl_xor(cm, 16));
      cm = fmaxf(cm, __shfl_xor(cm, 32));
      if (kb == 0 && j < Md) atomicMaxFloat(&cmax[j], cm);
    }
  }
}

// -------- generic 64x64 tiled fp32 GEMM ----
template <int SPLITK, int NT>
__global__ __launch_bounds__(256) void k_gemm64(const float* __restrict__ Am,
                                                const float* __restrict__ Bm,
                                                const float* __restrict__ bias,
                                                const float* __restrict__ kscale,
                                                float* __restrict__ C,
                                                int Mn, int Nn, int Kn, int relu) {
  __shared__ float As[16][68];
  __shared__ float Bs[16][68];
  int i0 = blockIdx.y * 64, j0 = blockIdx.x * 64;
  int kchunk = (Kn + SPLITK - 1) / SPLITK;
  int ks = blockIdx.z * kchunk;
  int ke = min(Kn, ks + kchunk);
  int tid = threadIdx.x;
  int tx = tid & 15, ty = tid >> 4;
  float acc[4][4] = {};
  for (int k0 = ks; k0 < ke; k0 += 16) {
#pragma unroll
    for (int l0 = 0; l0 < 1024; l0 += 256) {
      int l = l0 + tid;
      int i = l >> 4, k = l & 15;
      float v = 0.f;
      if (i0 + i < Mn && k0 + k < ke) {
        v = NT ? __builtin_nontemporal_load(&Am[(size_t)(i0 + i) * Kn + (k0 + k)])
               : Am[(size_t)(i0 + i) * Kn + (k0 + k)];
        if (kscale) v *= kscale[k0 + k];
      }
      As[k][i] = v;
    }
#pragma unroll
    for (int l0 = 0; l0 < 1024; l0 += 256) {
      int l = l0 + tid;
      int k = l >> 6, j = l & 63;
      float v = 0.f;
      if (k0 + k < ke && j0 + j < Nn) v = Bm[(size_t)(k0 + k) * Nn + (j0 + j)];
      Bs[k][j] = v;
    }
    __syncthreads();
#pragma unroll
    for (int k = 0; k < 16; ++k) {
      const float4 av = *(const float4*)&As[k][ty * 4];
      const float4 bv = *(const float4*)&Bs[k][tx * 4];
      float a_[4] = {av.x, av.y, av.z, av.w};
      float b_[4] = {bv.x, bv.y, bv.z, bv.w};
#pragma unroll
      for (int ri = 0; ri < 4; ++ri)
#pragma unroll
        for (int rj = 0; rj < 4; ++rj)
          acc[ri][rj] = fmaf(a_[ri], b_[rj], acc[ri][rj]);
    }
    __syncthreads();
  }
#pragma unroll
  for (int ri = 0; ri < 4; ++ri) {
    int i = i0 + ty * 4 + ri;
    if (i >= Mn) continue;
#pragma unroll
    for (int rj = 0; rj < 4; ++rj) {
      int j = j0 + tx * 4 + rj;
      if (j >= Nn) continue;
      float v = acc[ri][rj];
      if (SPLITK > 1) {
        atomicAdd(&C[(size_t)i * Nn + j], v);
      } else {
        if (bias) v += bias[j];
        if (relu) v = fmaxf(v, 0.f);
        C[(size_t)i * Nn + j] = v;
      }
    }
  }
}

__global__ void k_transpose(const float* __restrict__ in, float* __restrict__ out,
                            int rows, int cols) {
  __shared__ float tile[32][33];
  int c0 = blockIdx.x * 32, r0 = blockIdx.y * 32;
  int tx = threadIdx.x & 31, tg = threadIdx.x >> 5;
  for (int rr = tg; rr < 32; rr += 8) {
    int r = r0 + rr, c = c0 + tx;
    tile[rr][tx] = (r < rows && c < cols) ? in[(size_t)r * cols + c] : 0.f;
  }
  __syncthreads();
  for (int rr = tg; rr < 32; rr += 8) {
    int c = c0 + rr, r = r0 + tx;
    if (c < cols && r < rows) out[(size_t)c * rows + r] = tile[tx][rr];
  }
}

__global__ void k_softmax16(const float* __restrict__ X5, float* __restrict__ out, int rows) {
  int r = blockIdx.x * blockDim.x + threadIdx.x;
  if (r >= rows) return;
  float v[16];
  float m = -INFINITY;
#pragma unroll
  for (int c = 0; c < 16; ++c) { v[c] = X5[r * 16 + c]; m = fmaxf(m, v[c]); }
  float s = 0.f;
#pragma unroll
  for (int c = 0; c < 16; ++c) { v[c] = expf(v[c] - m); s += v[c]; }
  float inv = 1.f / s;
#pragma unroll
  for (int c = 0; c < 16; ++c) out[r * 16 + c] = v[c] * inv;
}

extern "C" void kernel_launch(void* const* d_in, const int* in_sizes, int n_in,
                              void* d_out, int out_size, void* d_ws, size_t ws_size,
                              hipStream_t stream) {
  const float* X     = (const float*)d_in[0];
  const float* Z     = (const float*)d_in[1];
  const float* adj_e = (const float*)d_in[2];
  const float* Tm    = (const float*)d_in[4];
  const int*   ei    = (const int*)d_in[5];
  const int* src = ei;
  const int* dst = ei + E2;
  const float* W1  = (const float*)d_in[6];
  const float* b1  = (const float*)d_in[7];
  const float* p2  = (const float*)d_in[8];
  const float* W2  = (const float*)d_in[9];
  const float* b2  = (const float*)d_in[10];
  const float* p3  = (const float*)d_in[11];
  const float* W3  = (const float*)d_in[12];
  const float* b3  = (const float*)d_in[13];
  const float* p32 = (const float*)d_in[14];
  const float* W32 = (const float*)d_in[15];
  const float* b32 = (const float*)d_in[16];
  const float* p4  = (const float*)d_in[17];
  const float* W4  = (const float*)d_in[18];
  const float* b4g = (const float*)d_in[19];
  const float* b4  = (const float*)d_in[20];
  const float* W5  = (const float*)d_in[21];
  const float* b5  = (const float*)d_in[22];

  char* wsb = (char*)d_ws;
  const bool big = ws_size >= (size_t)310 * 1024 * 1024;

  // ---- big layout (bytes) ----
  char* Apk  = wsb;                               // 72,384,512
  char* pAhi = wsb + APK_BYTES;                   // unscaled edge pack
  char* pBhi = pAhi + PKA_BYTES;                  // scaled edge pack
  char* Bpk  = wsb + 145539072;                   // 770,048
  // gc4 overlay (edge packs dead by then)
  char* mAhi = wsb;                               // 36,962,304
  char* mBhi = mAhi + PKM_BYTES;                  // ends 73,924,608
  char* Mpk  = wsb + 80000000;                    // 24*94*8192 = 18,481,152
  char* gpk  = wsb + 100000000;                   // 94*8192 = 770,048

  // small region at byte 182,000,000
  float* small = big ? (float*)(wsb + 182000000) : (float*)d_ws + 36000000;
  float* Xh   = small;
  float* xw   = small + 768000;
  float* Zh   = small + 1536000;
  float* HeW  = small + 1920000;
  float* Bc   = small + 2304000;
  float* g    = small + 2688000;
  float* sv   = small + 3072000;
  float* se   = small + 3076096;
  float* cmax = small + 3084288;
  float* dinv = small + 3090432;
  float* X5   = small + 3093504;
  // fallback-only overlays
  float* A_fb     = (float*)d_ws;
  float* Tt_fb    = (float*)d_ws;
  float* mult1_fb = (float*)d_ws + 18000000;
  float* out  = (float*)d_out;

  auto gemm = [&](const float* Am, const float* Bm, const float* bias, const float* ksc,
                  float* C, int Mn, int Nn, int Kn, int relu, int splitk, int nt) {
    dim3 gr(cdiv(Nn, 64), cdiv(Mn, 64), splitk);
    if (splitk == 1) {
      if (nt) k_gemm64<1, 1><<<gr, 256, 0, stream>>>(Am, Bm, bias, ksc, C, Mn, Nn, Kn, relu);
      else    k_gemm64<1, 0><<<gr, 256, 0, stream>>>(Am, Bm, bias, ksc, C, Mn, Nn, Kn, relu);
    } else {
      if (nt) k_gemm64<4, 1><<<gr, 256, 0, stream>>>(Am, Bm, bias, ksc, C, Mn, Nn, Kn, relu);
      else    k_gemm64<4, 0><<<gr, 256, 0, stream>>>(Am, Bm, bias, ksc, C, Mn, Nn, Kn, relu);
    }
  };

  // ---- degrees / norms ----
  k_fill<<<cdiv(NN, 256), 256, 0, stream>>>(dinv, 0.f, NN);
  k_deg_count<<<cdiv(E2, 256), 256, 0, stream>>>(dst, dinv, E2);
  k_dinv<<<cdiv(NN, 256), 256, 0, stream>>>(dinv, NN);

  // ---- gc1 ----
  gemm(X, W1, nullptr, nullptr, xw, NN, H1, FV, 0, 1, 0);
  k_gcn_init<<<cdiv(NN * H1, 256), 256, 0, stream>>>(xw, dinv, b1, Xh, NN, 8);
  k_gcn_scatter<<<cdiv(E2 * H1, 256), 256, 0, stream>>>(xw, src, dst, dinv, Xh, E2, 8);
  k_relu<<<cdiv(NN * H1, 256), 256, 0, stream>>>(Xh, NN * H1);
  k_relu_copy<<<cdiv(MM * FE, 256), 256, 0, stream>>>(Z, Zh, MM * FE);

  // ---- pack unscaled T, once ----
  if (big) {
    dim3 gp(CT_E, KT_E);
    k_pack_edge<<<gp, 256, 0, stream>>>(Tm, nullptr, pAhi, nullptr, nullptr, 0, MM, NN, KT_E);
  }

  // ---- edge layers gc2, gc3, gc3_2 ----
  const float* ep[3] = {p2, p3, p32};
  const float* eW[3] = {W2, W3, W32};
  const float* eb[3] = {b2, b3, b32};
  const int ntriE = CT_E * (CT_E + 1) / 2;   // 1128
  for (int L = 0; L < 3; ++L) {
    k_rowdot<<<cdiv(NN, 4), 256, 0, stream>>>(Xh, ep[L], sv, NN, H1);
    gemm(Zh, eW[L], nullptr, nullptr, HeW, MM, FE, FE, 0, 1, 0);
    if (big) {
      dim3 gs(CT_E, KT_E);
      k_scale_pack<<<gs, 256, 0, stream>>>(pAhi, pBhi, sv, cmax, KT_E, NN, MM);
      k_tsvt_sym<1><<<ntriE, 256, 0, stream>>>(pAhi, pBhi, adj_e, Apk, cmax,
                                               MM, KT_E, CT_E, KT_A);
      k_prep_pack<<<KT_A, 256, 0, stream>>>(HeW, cmax, eb[L], Zh, Bpk, MM);
      dim3 gz(CT_E, 8);
      k_zh<<<gz, 256, 0, stream>>>(Apk, Bpk, Zh, MM, KT_A, cdiv(KT_A, 8));
    } else {
      k_fill<<<cdiv(MM, 256), 256, 0, stream>>>(cmax, -INFINITY, MM);
      dim3 gm2(CT_E, CT_E);
      k_tsvt_cvt<1><<<gm2, 256, 0, stream>>>(Tm, sv, adj_e, A_fb, cmax, MM, NN);
      k_prep<<<cdiv(MM * FE, 256), 256, 0, stream>>>(HeW, cmax, eb[L], Bc, Zh, MM * FE);
      gemm(A_fb, Bc, nullptr, nullptr, Zh, MM, FE, MM, 0, 4, 1);
    }
    k_relu<<<cdiv(MM * FE, 256), 256, 0, stream>>>(Zh, MM * FE);
  }

  // ---- gc4 ----
  k_rowdot<<<cdiv(MM, 4), 256, 0, stream>>>(Zh, p4, se, MM, FE);
  gemm(Xh, W4, nullptr, nullptr, xw, NN, H2, H1, 0, 1, 0);
  k_gcn_init<<<cdiv(NN * H2, 256), 256, 0, stream>>>(xw, dinv, b4g, g, NN, 7);
  k_gcn_scatter<<<cdiv(E2 * H2, 256), 256, 0, stream>>>(xw, src, dst, dinv, g, E2, 7);
  if (big) {
    dim3 gp(CT_M, KT_M);
    k_pack_tt<<<gp, 256, 0, stream>>>(Tm, nullptr, mAhi, nullptr, 0, NN, MM, KT_M);
    dim3 gs(CT_M, KT_M);
    k_scale_pack<<<gs, 256, 0, stream>>>(mAhi, mBhi, se, nullptr, KT_M, MM, 0);
    const int ntriM = CT_M * (CT_M + 1) / 2;   // 300
    k_tsvt_sym<0><<<ntriM, 256, 0, stream>>>(mAhi, mBhi, nullptr, Mpk, nullptr,
                                             NN, KT_M, CT_M, NPK_M);
    k_pack_g<<<NPK_M, 256, 0, stream>>>(g, gpk, NN);
    k_fill_bias<<<cdiv(NN * H2, 256), 256, 0, stream>>>(Xh, b4, H2 - 1, NN * H2);
    dim3 gx(CT_M, 8);
    k_zh128<<<gx, 256, 0, stream>>>(Mpk, gpk, Xh, NN, NPK_M, cdiv(NPK_M, 8));
  } else {
    dim3 gt(cdiv(MM, 32), cdiv(NN, 32));
    k_transpose<<<gt, 256, 0, stream>>>(Tm, Tt_fb, NN, MM);
    dim3 gm1(cdiv(NN, 128), cdiv(NN, 128));
    k_tsvt_cvt<0><<<gm1, 256, 0, stream>>>(Tt_fb, se, nullptr, mult1_fb, nullptr, NN, MM);
    k_fill_bias<<<cdiv(NN * H2, 256), 256, 0, stream>>>(Xh, b4, H2 - 1, NN * H2);
    gemm(mult1_fb, g, nullptr, nullptr, Xh, NN, H2, NN, 0, 4, 0);
  }
  k_relu<<<cdiv(NN * H2, 256), 256, 0, stream>>>(Xh, NN * H2);

  // ---- gc5 + softmax ----
  gemm(Xh, W5, nullptr, nullptr, xw, NN, NC, H2, 0, 1, 0);
  k_gcn_init<<<cdiv(NN * NC, 256), 256, 0, stream>>>(xw, dinv, b5, X5, NN, 4);
  k_gcn_scatter<<<cdiv(E2 * NC, 256), 256, 0, stream>>>(xw, src, dst, dinv, X5, E2, 4);
  k_softmax16<<<cdiv(NN, 256), 256, 0, stream>>>(X5, out, NN);
}